// Round 4
// baseline (277.606 us; speedup 1.0000x reference)
//
#include <hip/hip_runtime.h>
#include <hip/hip_bf16.h>
#include <math.h>

#define Bc 32
#define Rc 200
#define Nc 200
#define Dc 128
#define Hc 8
#define QKc 16
#define Kc 10
#define BRc (Bc*Rc)

typedef __attribute__((ext_vector_type(8))) short short8;
typedef __attribute__((ext_vector_type(4))) float f32x4;

#define GLOAD_LDS16(g, l) __builtin_amdgcn_global_load_lds( \
    (const __attribute__((address_space(1))) void*)(g), \
    (__attribute__((address_space(3))) void*)(l), 16, 0, 0)

// ---------------------------------------------------------------------------
// 32x32 transpose+convert tile helper (block-uniform call sites only)
// ---------------------------------------------------------------------------
__device__ inline void transpose_tile(const float* __restrict__ src, int lds_,
                                      __hip_bfloat16* __restrict__ dst, int ldd,
                                      int k0, int n0)
{
    __shared__ float tile[32][33];
    int tx = threadIdx.x & 31, ty = threadIdx.x >> 5;  // 32 x 8
    #pragma unroll
    for (int i = ty; i < 32; i += 8)
        tile[i][tx] = src[(size_t)(k0 + i) * lds_ + n0 + tx];
    __syncthreads();
    #pragma unroll
    for (int i = ty; i < 32; i += 8)
        dst[(size_t)(n0 + i) * ldd + k0 + tx] = __float2bfloat16(tile[tx][i]);
}

// ---------------------------------------------------------------------------
// Kernel P: all weight preprocessing in ONE launch (role = blockIdx.x range).
//  [0,800)   W1[1280][640]  -> W1t[640][1280] bf16
//  [800,816) Wk[128][128]   -> Wkvt rows 0:128
//  [816,832) Wv[128][128]   -> Wkvt rows 128:256
//  [832,848) Wmhc           -> Wmt
//  [848,864) Wq rows 0:128  -> Wcat[n][0:128]      (Wq_top^T)
//  [864,904) Wfused = W2 @ Wq_bot (fp32) -> Wcat[n][128:768]
//  [904,929) enc fp32 -> encb bf16 (819200 elems)
//  [929]     bq[n] = sum_k b2[k]*Wq[128+k][n]
// ---------------------------------------------------------------------------
__global__ __launch_bounds__(256) void prep_kernel(
    const float* __restrict__ W1, const float* __restrict__ W2,
    const float* __restrict__ Wq, const float* __restrict__ Wmhc,
    const float* __restrict__ Wk, const float* __restrict__ Wv,
    const float* __restrict__ b2, const float* __restrict__ enc,
    __hip_bfloat16* __restrict__ W1t, __hip_bfloat16* __restrict__ Wkvt,
    __hip_bfloat16* __restrict__ Wmt, __hip_bfloat16* __restrict__ Wcat,
    float* __restrict__ bq, __hip_bfloat16* __restrict__ encb)
{
    int bid = blockIdx.x;
    int t = threadIdx.x;
    if (bid < 800) {
        transpose_tile(W1, 640, W1t, 1280, (bid % 40) * 32, (bid / 40) * 32);
    } else if (bid < 816) {
        int id = bid - 800;
        transpose_tile(Wk, 128, Wkvt, 128, (id & 3) * 32, (id >> 2) * 32);
    } else if (bid < 832) {
        int id = bid - 816;
        transpose_tile(Wv, 128, Wkvt + 128 * 128, 128, (id & 3) * 32, (id >> 2) * 32);
    } else if (bid < 848) {
        int id = bid - 832;
        transpose_tile(Wmhc, 128, Wmt, 128, (id & 3) * 32, (id >> 2) * 32);
    } else if (bid < 864) {
        int id = bid - 848;
        transpose_tile(Wq, 128, Wcat, 768, (id & 3) * 32, (id >> 2) * 32);
    } else if (bid < 904) {
        int j0 = (bid - 864) * 16;
        int n = t & 127, half = t >> 7;
        #pragma unroll
        for (int jj = 0; jj < 8; ++jj) {
            int j = j0 + half * 8 + jj;
            float acc = 0.f;
            for (int k = 0; k < 128; ++k)
                acc = fmaf(W2[(size_t)j * 128 + k], Wq[(size_t)(128 + k) * 128 + n], acc);
            Wcat[(size_t)n * 768 + 128 + j] = __float2bfloat16(acc);
        }
    } else if (bid < 929) {
        size_t base = (size_t)(bid - 904) * 32768 + (size_t)t * 4;
        #pragma unroll 4
        for (int it = 0; it < 32; ++it) {
            size_t i = base + (size_t)it * 1024;
            float4 v = *(const float4*)(enc + i);
            encb[i + 0] = __float2bfloat16(v.x);
            encb[i + 1] = __float2bfloat16(v.y);
            encb[i + 2] = __float2bfloat16(v.z);
            encb[i + 3] = __float2bfloat16(v.w);
        }
    } else {
        if (t < 128) {
            float acc = 0.f;
            for (int k = 0; k < 128; ++k)
                acc = fmaf(b2[k], Wq[(size_t)(128 + k) * 128 + t], acc);
            bq[t] = acc;
        }
    }
}

// ---------------------------------------------------------------------------
// Kernel 1: kNN top-10 (JAX tie-break: lower index wins), gather, pad-mean,
// write bmat[BR,1280] (bf16); cur_emb -> hq[:,0:128] (bf16, row stride 768).
// ---------------------------------------------------------------------------
__global__ __launch_bounds__(128) void knn_gather_kernel(
    const float* __restrict__ enc, const float* __restrict__ dist,
    const float* __restrict__ mask, const int* __restrict__ cur,
    __hip_bfloat16* __restrict__ bmat, __hip_bfloat16* __restrict__ hq)
{
    int br = blockIdx.x;
    int b = br / Rc;
    int t = threadIdx.x;
    __shared__ int s_idx[Kc];
    __shared__ float s_part[2][Kc];
    __shared__ float s_row[Kc];

    int c = cur[br];
    const float* drow = dist + ((size_t)b * Nc + c) * Nc;
    const float* mrow = mask + (size_t)br * Nc;

    if (t < 64) {
        float v[4];
        #pragma unroll
        for (int j = 0; j < 4; ++j) {
            int n = t + 64 * j;
            float val = INFINITY;
            if (n < Nc) {
                float mv = mrow[n];
                if (!isinf(mv)) val = drow[n];
            }
            v[j] = val;
        }
        for (int k = 0; k < Kc; ++k) {
            float bv = v[0]; int bn = t;
            #pragma unroll
            for (int j = 1; j < 4; ++j) {
                if (v[j] < bv) { bv = v[j]; bn = t + 64 * j; }
            }
            #pragma unroll
            for (int off = 32; off > 0; off >>= 1) {
                float ov = __shfl_xor(bv, off);
                int   on = __shfl_xor(bn, off);
                if (ov < bv || (ov == bv && on < bn)) { bv = ov; bn = on; }
            }
            if (t == 0) s_idx[k] = isinf(bv) ? Nc : bn;
            int oj = bn >> 6, ol = bn & 63;
            if (t == ol) v[oj] = INFINITY;
        }
    }
    __syncthreads();

    float col[Kc]; float colsum = 0.f;
    #pragma unroll
    for (int k = 0; k < Kc; ++k) {
        int idx = s_idx[k];
        float val = 0.f;
        if (idx < Nc) val = enc[((size_t)b * Nc + idx) * Dc + t];
        col[k] = val; colsum += val;
    }
    int wave = t >> 6, lane = t & 63;
    #pragma unroll
    for (int k = 0; k < Kc; ++k) {
        float sv = col[k];
        #pragma unroll
        for (int off = 32; off > 0; off >>= 1) sv += __shfl_xor(sv, off);
        if (lane == 0) s_part[wave][k] = sv;
    }
    __syncthreads();
    if (t < Kc) s_row[t] = s_part[0][t] + s_part[1][t];
    __syncthreads();

    float cnt = 0.f;
    #pragma unroll
    for (int k = 0; k < Kc; ++k) cnt += (s_row[k] != 0.f) ? 1.f : 0.f;
    float mean = colsum / fmaxf(cnt, 1e-9f);

    __hip_bfloat16* brow = bmat + (size_t)br * (Kc * Dc);
    #pragma unroll
    for (int k = 0; k < Kc; ++k)
        brow[k * Dc + t] = __float2bfloat16((s_row[k] == 0.f) ? mean : col[k]);

    hq[(size_t)br * 768 + t] = __float2bfloat16(enc[((size_t)b * Nc + c) * Dc + t]);
}

// ---------------------------------------------------------------------------
// Kernel 3: bf16 MFMA GEMM. C = (relu)(A @ Bt^T + bias).
// 128x128 block tile, 4 waves x (64x64), 16x16x32 MFMA, global_load_lds w=16,
// column-group swizzle -> 2-way LDS conflicts (free).
// ---------------------------------------------------------------------------
template<bool RELU, bool HASBIAS, bool OUTBF16>
__global__ __launch_bounds__(256) void mfma_gemm_kernel(
    const __hip_bfloat16* __restrict__ A, int lda,
    const __hip_bfloat16* __restrict__ Bt, int Kdim,
    const float* __restrict__ bias,
    void* __restrict__ Cout, int ldc, int coff)
{
    __shared__ short Asl[128 * 32];
    __shared__ short Bsl[128 * 32];
    int tid = threadIdx.x;
    int wave = tid >> 6, lane = tid & 63;
    int m0 = blockIdx.x * 128, n0 = blockIdx.y * 128;

    int lrow = lane >> 2;
    int cg   = lane & 3;
    int ss   = (lane >> 3) & 3;
    int gq   = (cg - ss) & 3;
    const short* Ab = (const short*)A;
    const short* Bb = (const short*)Bt;
    const short* gA0 = Ab + (size_t)(m0 + wave * 32 + lrow) * lda + gq * 8;
    const short* gA1 = gA0 + (size_t)16 * lda;
    const short* gB0 = Bb + (size_t)(n0 + wave * 32 + lrow) * Kdim + gq * 8;
    const short* gB1 = gB0 + (size_t)16 * Kdim;
    short* lA0 = &Asl[(wave * 32) * 32];
    short* lA1 = &Asl[(wave * 32 + 16) * 32];
    short* lB0 = &Bsl[(wave * 32) * 32];
    short* lB1 = &Bsl[(wave * 32 + 16) * 32];

    int wm = wave >> 1, wn = wave & 1;
    int rrow = lane & 15, quad = lane >> 4;
    int srd  = (rrow >> 1) & 3;

    f32x4 acc[4][4];
    #pragma unroll
    for (int i = 0; i < 4; ++i)
        #pragma unroll
        for (int j = 0; j < 4; ++j)
            acc[i][j] = (f32x4){0.f, 0.f, 0.f, 0.f};

    for (int k0 = 0; k0 < Kdim; k0 += 32) {
        __syncthreads();
        GLOAD_LDS16(gA0 + k0, lA0);
        GLOAD_LDS16(gA1 + k0, lA1);
        GLOAD_LDS16(gB0 + k0, lB0);
        GLOAD_LDS16(gB1 + k0, lB1);
        __syncthreads();
        short8 afr[4], bfr[4];
        #pragma unroll
        for (int mt = 0; mt < 4; ++mt) {
            int rowa = wm * 64 + mt * 16 + rrow;
            afr[mt] = *(const short8*)&Asl[rowa * 32 + ((quad + srd) & 3) * 8];
            int rowb = wn * 64 + mt * 16 + rrow;
            bfr[mt] = *(const short8*)&Bsl[rowb * 32 + ((quad + srd) & 3) * 8];
        }
        #pragma unroll
        for (int mt = 0; mt < 4; ++mt)
            #pragma unroll
            for (int nt = 0; nt < 4; ++nt)
                acc[mt][nt] = __builtin_amdgcn_mfma_f32_16x16x32_bf16(
                    afr[mt], bfr[nt], acc[mt][nt], 0, 0, 0);
    }

    #pragma unroll
    for (int mt = 0; mt < 4; ++mt) {
        #pragma unroll
        for (int nt = 0; nt < 4; ++nt) {
            int n = wn * 64 + nt * 16 + rrow;
            float bv = HASBIAS ? bias[n0 + n] : 0.f;
            #pragma unroll
            for (int i = 0; i < 4; ++i) {
                int m = m0 + wm * 64 + mt * 16 + quad * 4 + i;
                float v = acc[mt][nt][i] + bv;
                if (RELU) v = fmaxf(v, 0.f);
                size_t off = (size_t)m * ldc + coff + n0 + n;
                if (OUTBF16) ((__hip_bfloat16*)Cout)[off] = __float2bfloat16(v);
                else         ((float*)Cout)[off] = v;
            }
        }
    }
}

// ---------------------------------------------------------------------------
// Kernel 4: attention per (b,h). 4 threads per query row, each owns a 50-wide
// n-chunk with local online softmax; 4-lane shuffle merge. K/V from kvf
// ([m][0:128]=k, [m][128:256]=v, bf16), fp32 float4 rows in LDS (stride 5).
// ---------------------------------------------------------------------------
__global__ __launch_bounds__(832) void attn_kernel(
    const float* __restrict__ q, const __hip_bfloat16* __restrict__ kvf,
    const float* __restrict__ mask, __hip_bfloat16* __restrict__ att)
{
    int b = blockIdx.x / Hc, h = blockIdx.x % Hc;
    __shared__ float4 sk[Nc][5];
    __shared__ float4 sv[Nc][5];
    int t = threadIdx.x;

    for (int i = t; i < Nc * 4; i += 832) {
        int n = i >> 2, g = i & 3;
        const __hip_bfloat16* kr = kvf + ((size_t)b * Nc + n) * 256 + h * QKc + g * 4;
        const __hip_bfloat16* vr = kr + 128;
        sk[n][g] = make_float4(__bfloat162float(kr[0]), __bfloat162float(kr[1]),
                               __bfloat162float(kr[2]), __bfloat162float(kr[3]));
        sv[n][g] = make_float4(__bfloat162float(vr[0]), __bfloat162float(vr[1]),
                               __bfloat162float(vr[2]), __bfloat162float(vr[3]));
    }
    __syncthreads();

    int r = t >> 2, c = t & 3;
    if (r < Rc) {
        float4 q0, q1, q2, q3;
        {
            const float* qrow = q + ((size_t)b * Rc + r) * 128 + h * QKc;
            q0 = *(const float4*)(qrow + 0);
            q1 = *(const float4*)(qrow + 4);
            q2 = *(const float4*)(qrow + 8);
            q3 = *(const float4*)(qrow + 12);
        }
        const float* mrow = mask + ((size_t)b * Rc + r) * Nc;
        float m = -INFINITY, l = 0.f, o[QKc] = {};
        int n1 = c * 50 + 50;
        for (int n = c * 50; n < n1; ++n) {
            float4 k0 = sk[n][0], k1 = sk[n][1], k2 = sk[n][2], k3 = sk[n][3];
            float s = q0.x * k0.x + q0.y * k0.y + q0.z * k0.z + q0.w * k0.w
                    + q1.x * k1.x + q1.y * k1.y + q1.z * k1.z + q1.w * k1.w
                    + q2.x * k2.x + q2.y * k2.y + q2.z * k2.z + q2.w * k2.w
                    + q3.x * k3.x + q3.y * k3.y + q3.z * k3.z + q3.w * k3.w;
            s = s * 0.25f + mrow[n];
            float mnew = fmaxf(m, s);
            float alpha, p;
            if (mnew == -INFINITY) { alpha = 1.f; p = 0.f; }
            else { alpha = expf(m - mnew); p = expf(s - mnew); }
            l = l * alpha + p;
            float4 v0 = sv[n][0], v1 = sv[n][1], v2 = sv[n][2], v3 = sv[n][3];
            o[0]  = o[0]  * alpha + p * v0.x;  o[1]  = o[1]  * alpha + p * v0.y;
            o[2]  = o[2]  * alpha + p * v0.z;  o[3]  = o[3]  * alpha + p * v0.w;
            o[4]  = o[4]  * alpha + p * v1.x;  o[5]  = o[5]  * alpha + p * v1.y;
            o[6]  = o[6]  * alpha + p * v1.z;  o[7]  = o[7]  * alpha + p * v1.w;
            o[8]  = o[8]  * alpha + p * v2.x;  o[9]  = o[9]  * alpha + p * v2.y;
            o[10] = o[10] * alpha + p * v2.z;  o[11] = o[11] * alpha + p * v2.w;
            o[12] = o[12] * alpha + p * v3.x;  o[13] = o[13] * alpha + p * v3.y;
            o[14] = o[14] * alpha + p * v3.z;  o[15] = o[15] * alpha + p * v3.w;
            m = mnew;
        }
        float M = m;
        M = fmaxf(M, __shfl_xor(M, 1));
        M = fmaxf(M, __shfl_xor(M, 2));
        float sc = (m == -INFINITY) ? 0.f : expf(m - M);
        l *= sc;
        l += __shfl_xor(l, 1);
        l += __shfl_xor(l, 2);
        #pragma unroll
        for (int j = 0; j < QKc; ++j) {
            float oj = o[j] * sc;
            oj += __shfl_xor(oj, 1);
            oj += __shfl_xor(oj, 2);
            o[j] = oj;
        }
        if (c == 0) {
            float inv = (l > 0.f) ? 1.f / l : 0.f;
            __hip_bfloat16* arow = att + ((size_t)b * Rc + r) * 128 + h * QKc;
            #pragma unroll
            for (int j = 0; j < QKc; ++j) arow[j] = __float2bfloat16(o[j] * inv);
        }
    }
}

// ---------------------------------------------------------------------------
// Kernel 5: logits = 10*tanh((mh @ enc^T)/sqrt(128)) + mask -> d_out.
// ---------------------------------------------------------------------------
__global__ __launch_bounds__(256) void final_logits_kernel(
    const float* __restrict__ mh, const float* __restrict__ enc,
    const float* __restrict__ mask, float* __restrict__ out)
{
    int b = blockIdx.x;
    int r0 = blockIdx.y * 64;
    int n0 = blockIdx.z * 32;
    __shared__ float smhT[Dc][68];
    __shared__ float senT[Dc][36];
    int t = threadIdx.x;
    for (int i = t; i < 64 * 32; i += 256) {
        int rr = i >> 5, dq = i & 31;
        int r = r0 + rr;
        float4 v = make_float4(0.f, 0.f, 0.f, 0.f);
        if (r < Rc) v = *(const float4*)(mh + ((size_t)b * Rc + r) * Dc + dq * 4);
        smhT[dq * 4 + 0][rr] = v.x; smhT[dq * 4 + 1][rr] = v.y;
        smhT[dq * 4 + 2][rr] = v.z; smhT[dq * 4 + 3][rr] = v.w;
    }
    for (int i = t; i < 32 * 32; i += 256) {
        int nn = i >> 5, dq = i & 31;
        int n = n0 + nn;
        float4 v = make_float4(0.f, 0.f, 0.f, 0.f);
        if (n < Nc) v = *(const float4*)(enc + ((size_t)b * Nc + n) * Dc + dq * 4);
        senT[dq * 4 + 0][nn] = v.x; senT[dq * 4 + 1][nn] = v.y;
        senT[dq * 4 + 2][nn] = v.z; senT[dq * 4 + 3][nn] = v.w;
    }
    __syncthreads();
    int tx = t & 7;
    int ty = t >> 3;
    float acc[2][4] = {};
    #pragma unroll 4
    for (int d = 0; d < Dc; ++d) {
        float2 a  = *(const float2*)(&smhT[d][ty * 2]);
        float4 bb = *(const float4*)(&senT[d][tx * 4]);
        acc[0][0] = fmaf(a.x, bb.x, acc[0][0]);
        acc[0][1] = fmaf(a.x, bb.y, acc[0][1]);
        acc[0][2] = fmaf(a.x, bb.z, acc[0][2]);
        acc[0][3] = fmaf(a.x, bb.w, acc[0][3]);
        acc[1][0] = fmaf(a.y, bb.x, acc[1][0]);
        acc[1][1] = fmaf(a.y, bb.y, acc[1][1]);
        acc[1][2] = fmaf(a.y, bb.z, acc[1][2]);
        acc[1][3] = fmaf(a.y, bb.w, acc[1][3]);
    }
    const float scale = 0.08838834764831843f;
    #pragma unroll
    for (int i = 0; i < 2; ++i) {
        int r = r0 + ty * 2 + i;
        #pragma unroll
        for (int j = 0; j < 4; ++j) {
            int n = n0 + tx * 4 + j;
            if (r < Rc && n < Nc) {
                float lg = 10.f * tanhf(acc[i][j] * scale)
                         + mask[((size_t)b * Rc + r) * Nc + n];
                out[((size_t)b * Rc + r) * Nc + n] = lg;
            }
        }
    }
}

// ---------------------------------------------------------------------------
// Kernel 6: row softmax over N=200, in place.
// ---------------------------------------------------------------------------
__global__ __launch_bounds__(64) void softmax_kernel(float* __restrict__ out)
{
    int br = blockIdx.x;
    float* row = out + (size_t)br * Nc;
    int t = threadIdx.x;
    float v[4]; float m = -INFINITY;
    #pragma unroll
    for (int j = 0; j < 4; ++j) {
        int n = t + 64 * j;
        v[j] = (n < Nc) ? row[n] : -INFINITY;
        m = fmaxf(m, v[j]);
    }
    #pragma unroll
    for (int off = 32; off > 0; off >>= 1) m = fmaxf(m, __shfl_xor(m, off));
    float e[4]; float s = 0.f;
    #pragma unroll
    for (int j = 0; j < 4; ++j) {
        e[j] = (v[j] == -INFINITY) ? 0.f : expf(v[j] - m);
        s += e[j];
    }
    #pragma unroll
    for (int off = 32; off > 0; off >>= 1) s += __shfl_xor(s, off);
    float inv = 1.f / s;
    #pragma unroll
    for (int j = 0; j < 4; ++j) {
        int n = t + 64 * j;
        if (n < Nc) row[n] = e[j] * inv;
    }
}

// ---------------------------------------------------------------------------
extern "C" void kernel_launch(void* const* d_in, const int* in_sizes, int n_in,
                              void* d_out, int out_size, void* d_ws, size_t ws_size,
                              hipStream_t stream)
{
    const float* enc  = (const float*)d_in[0];
    const float* dist = (const float*)d_in[1];
    const float* mask = (const float*)d_in[2];
    const int*   cur  = (const int*)d_in[3];
    const float* Wq   = (const float*)d_in[4];
    const float* Wk   = (const float*)d_in[5];
    const float* Wv   = (const float*)d_in[6];
    const float* Wmhc = (const float*)d_in[7];
    const float* bmhc = (const float*)d_in[8];
    const float* W1   = (const float*)d_in[9];
    const float* b1   = (const float*)d_in[10];
    const float* W2   = (const float*)d_in[11];
    const float* b2   = (const float*)d_in[12];
    float* out = (float*)d_out;

    char* ws = (char*)d_ws;
    size_t off = 0;
    auto alloc = [&](size_t bytes) { char* p = ws + off; off += (bytes + 255) & ~(size_t)255; return p; };
    __hip_bfloat16* W1t  = (__hip_bfloat16*)alloc((size_t)640 * 1280 * 2);
    __hip_bfloat16* Wkvt = (__hip_bfloat16*)alloc((size_t)256 * 128 * 2);
    __hip_bfloat16* Wmt  = (__hip_bfloat16*)alloc((size_t)128 * 128 * 2);
    __hip_bfloat16* Wcat = (__hip_bfloat16*)alloc((size_t)128 * 768 * 2);
    float* bq = (float*)alloc((size_t)128 * 4);
    __hip_bfloat16* encb = (__hip_bfloat16*)alloc((size_t)Bc * Nc * Dc * 2);
    __hip_bfloat16* bmat = (__hip_bfloat16*)alloc((size_t)BRc * 1280 * 2);
    __hip_bfloat16* hq   = (__hip_bfloat16*)alloc((size_t)BRc * 768 * 2);
    float* q   = (float*)alloc((size_t)BRc * 128 * 4);
    __hip_bfloat16* kvf = (__hip_bfloat16*)alloc((size_t)Bc * Nc * 256 * 2);
    __hip_bfloat16* att = (__hip_bfloat16*)alloc((size_t)BRc * 128 * 2);
    float* mh  = (float*)alloc((size_t)BRc * 128 * 4);

    // 1) all weight preprocessing in one launch
    prep_kernel<<<930, 256, 0, stream>>>(W1, W2, Wq, Wmhc, Wk, Wv, b2, enc,
                                         W1t, Wkvt, Wmt, Wcat, bq, encb);
    // 2) kNN select + gather (writes bmat, hq[:,0:128])
    knn_gather_kernel<<<BRc, 128, 0, stream>>>(enc, dist, mask, cur, bmat, hq);
    // 3) kvf = enc @ [Wk|Wv]   [6400,128]x[128,256] -> bf16
    mfma_gemm_kernel<false, false, true><<<dim3((Bc * Nc) / 128, 2), 256, 0, stream>>>(
        encb, 128, Wkvt, 128, nullptr, kvf, 256, 0);
    // 4) hq[:,128:768] = relu(bmat @ W1 + b1)   [6400,1280]x[1280,640] -> bf16
    mfma_gemm_kernel<true, true, true><<<dim3(BRc / 128, 640 / 128), 256, 0, stream>>>(
        bmat, 1280, W1t, 1280, b1, hq, 768, 128);
    // 5) q = hq @ Wcat^T + bq   [6400,768]x[768,128] -> fp32  (folds W2 & Wq)
    mfma_gemm_kernel<false, true, false><<<dim3(BRc / 128, 1), 256, 0, stream>>>(
        hq, 768, Wcat, 768, bq, q, 128, 0);
    // 6) attention
    attn_kernel<<<Bc * Hc, 832, 0, stream>>>(q, kvf, mask, att);
    // 7) mh = att @ Wmhc + b_mhc
    mfma_gemm_kernel<false, true, false><<<dim3(BRc / 128, 1), 256, 0, stream>>>(
        att, 128, Wmt, 128, bmhc, mh, 128, 0);
    // 8) logits
    final_logits_kernel<<<dim3(Bc, 4, 7), 256, 0, stream>>>(mh, enc, mask, out);
    // 9) softmax
    softmax_kernel<<<BRc, 64, 0, stream>>>(out);
}

// Round 5
// 272.320 us; speedup vs baseline: 1.0194x; 1.0194x over previous
//
#include <hip/hip_runtime.h>
#include <hip/hip_bf16.h>
#include <math.h>

#define Bc 32
#define Rc 200
#define Nc 200
#define Dc 128
#define Hc 8
#define QKc 16
#define Kc 10
#define BRc (Bc*Rc)

typedef __attribute__((ext_vector_type(8))) short short8;
typedef __attribute__((ext_vector_type(4))) float f32x4;
typedef unsigned long long u64;

#define GLOAD_LDS16(g, l) __builtin_amdgcn_global_load_lds( \
    (const __attribute__((address_space(1))) void*)(g), \
    (__attribute__((address_space(3))) void*)(l), 16, 0, 0)

// ---------------------------------------------------------------------------
// 32x32 transpose+convert tile helper (block-uniform call sites only)
// ---------------------------------------------------------------------------
__device__ inline void transpose_tile(const float* __restrict__ src, int lds_,
                                      __hip_bfloat16* __restrict__ dst, int ldd,
                                      int k0, int n0)
{
    __shared__ float tile[32][33];
    int tx = threadIdx.x & 31, ty = threadIdx.x >> 5;  // 32 x 8
    #pragma unroll
    for (int i = ty; i < 32; i += 8)
        tile[i][tx] = src[(size_t)(k0 + i) * lds_ + n0 + tx];
    __syncthreads();
    #pragma unroll
    for (int i = ty; i < 32; i += 8)
        dst[(size_t)(n0 + i) * ldd + k0 + tx] = __float2bfloat16(tile[tx][i]);
}

// ---------------------------------------------------------------------------
// Kernel P: all weight preprocessing in ONE launch (role = blockIdx.x range).
// ---------------------------------------------------------------------------
__global__ __launch_bounds__(256) void prep_kernel(
    const float* __restrict__ W1, const float* __restrict__ W2,
    const float* __restrict__ Wq, const float* __restrict__ Wmhc,
    const float* __restrict__ Wk, const float* __restrict__ Wv,
    const float* __restrict__ b2, const float* __restrict__ enc,
    __hip_bfloat16* __restrict__ W1t, __hip_bfloat16* __restrict__ Wkvt,
    __hip_bfloat16* __restrict__ Wmt, __hip_bfloat16* __restrict__ Wcat,
    float* __restrict__ bq, __hip_bfloat16* __restrict__ encb)
{
    int bid = blockIdx.x;
    int t = threadIdx.x;
    if (bid < 800) {
        transpose_tile(W1, 640, W1t, 1280, (bid % 40) * 32, (bid / 40) * 32);
    } else if (bid < 816) {
        int id = bid - 800;
        transpose_tile(Wk, 128, Wkvt, 128, (id & 3) * 32, (id >> 2) * 32);
    } else if (bid < 832) {
        int id = bid - 816;
        transpose_tile(Wv, 128, Wkvt + 128 * 128, 128, (id & 3) * 32, (id >> 2) * 32);
    } else if (bid < 848) {
        int id = bid - 832;
        transpose_tile(Wmhc, 128, Wmt, 128, (id & 3) * 32, (id >> 2) * 32);
    } else if (bid < 864) {
        int id = bid - 848;
        transpose_tile(Wq, 128, Wcat, 768, (id & 3) * 32, (id >> 2) * 32);
    } else if (bid < 904) {
        int j0 = (bid - 864) * 16;
        int n = t & 127, half = t >> 7;
        #pragma unroll
        for (int jj = 0; jj < 8; ++jj) {
            int j = j0 + half * 8 + jj;
            float acc = 0.f;
            for (int k = 0; k < 128; ++k)
                acc = fmaf(W2[(size_t)j * 128 + k], Wq[(size_t)(128 + k) * 128 + n], acc);
            Wcat[(size_t)n * 768 + 128 + j] = __float2bfloat16(acc);
        }
    } else if (bid < 929) {
        size_t base = (size_t)(bid - 904) * 32768 + (size_t)t * 4;
        #pragma unroll 4
        for (int it = 0; it < 32; ++it) {
            size_t i = base + (size_t)it * 1024;
            float4 v = *(const float4*)(enc + i);
            encb[i + 0] = __float2bfloat16(v.x);
            encb[i + 1] = __float2bfloat16(v.y);
            encb[i + 2] = __float2bfloat16(v.z);
            encb[i + 3] = __float2bfloat16(v.w);
        }
    } else {
        if (t < 128) {
            float acc = 0.f;
            for (int k = 0; k < 128; ++k)
                acc = fmaf(b2[k], Wq[(size_t)(128 + k) * 128 + t], acc);
            bq[t] = acc;
        }
    }
}

// ---------------------------------------------------------------------------
// Kernel 1: kNN top-10 + gather + pad-mean -> bmat; cur_emb -> hq[:,0:128];
// ALSO emits allowed-bitmask maskbits[br][4] (u64) from the mask rows it
// already reads (one __ballot per 64-lane group).
// ---------------------------------------------------------------------------
__global__ __launch_bounds__(128) void knn_gather_kernel(
    const float* __restrict__ enc, const float* __restrict__ dist,
    const float* __restrict__ mask, const int* __restrict__ cur,
    __hip_bfloat16* __restrict__ bmat, __hip_bfloat16* __restrict__ hq,
    u64* __restrict__ maskbits)
{
    int br = blockIdx.x;
    int b = br / Rc;
    int t = threadIdx.x;
    __shared__ int s_idx[Kc];
    __shared__ float s_part[2][Kc];
    __shared__ float s_row[Kc];

    int c = cur[br];
    const float* drow = dist + ((size_t)b * Nc + c) * Nc;
    const float* mrow = mask + (size_t)br * Nc;

    if (t < 64) {
        float v[4];
        #pragma unroll
        for (int j = 0; j < 4; ++j) {
            int n = t + 64 * j;
            bool allowed = false;
            float val = INFINITY;
            if (n < Nc) {
                float mv = mrow[n];
                if (!isinf(mv)) { val = drow[n]; allowed = true; }
            }
            v[j] = val;
            u64 w = __ballot(allowed);
            if (t == 0) maskbits[(size_t)br * 4 + j] = w;
        }
        for (int k = 0; k < Kc; ++k) {
            float bv = v[0]; int bn = t;
            #pragma unroll
            for (int j = 1; j < 4; ++j) {
                if (v[j] < bv) { bv = v[j]; bn = t + 64 * j; }
            }
            #pragma unroll
            for (int off = 32; off > 0; off >>= 1) {
                float ov = __shfl_xor(bv, off);
                int   on = __shfl_xor(bn, off);
                if (ov < bv || (ov == bv && on < bn)) { bv = ov; bn = on; }
            }
            if (t == 0) s_idx[k] = isinf(bv) ? Nc : bn;
            int oj = bn >> 6, ol = bn & 63;
            if (t == ol) v[oj] = INFINITY;
        }
    }
    __syncthreads();

    float col[Kc]; float colsum = 0.f;
    #pragma unroll
    for (int k = 0; k < Kc; ++k) {
        int idx = s_idx[k];
        float val = 0.f;
        if (idx < Nc) val = enc[((size_t)b * Nc + idx) * Dc + t];
        col[k] = val; colsum += val;
    }
    int wave = t >> 6, lane = t & 63;
    #pragma unroll
    for (int k = 0; k < Kc; ++k) {
        float sv = col[k];
        #pragma unroll
        for (int off = 32; off > 0; off >>= 1) sv += __shfl_xor(sv, off);
        if (lane == 0) s_part[wave][k] = sv;
    }
    __syncthreads();
    if (t < Kc) s_row[t] = s_part[0][t] + s_part[1][t];
    __syncthreads();

    float cnt = 0.f;
    #pragma unroll
    for (int k = 0; k < Kc; ++k) cnt += (s_row[k] != 0.f) ? 1.f : 0.f;
    float mean = colsum / fmaxf(cnt, 1e-9f);

    __hip_bfloat16* brow = bmat + (size_t)br * (Kc * Dc);
    #pragma unroll
    for (int k = 0; k < Kc; ++k)
        brow[k * Dc + t] = __float2bfloat16((s_row[k] == 0.f) ? mean : col[k]);

    hq[(size_t)br * 768 + t] = __float2bfloat16(enc[((size_t)b * Nc + c) * Dc + t]);
}

// ---------------------------------------------------------------------------
// Kernel 3: bf16 MFMA GEMM. C = (relu)(A @ Bt^T + bias).
// ---------------------------------------------------------------------------
template<bool RELU, bool HASBIAS, bool OUTBF16>
__global__ __launch_bounds__(256) void mfma_gemm_kernel(
    const __hip_bfloat16* __restrict__ A, int lda,
    const __hip_bfloat16* __restrict__ Bt, int Kdim,
    const float* __restrict__ bias,
    void* __restrict__ Cout, int ldc, int coff)
{
    __shared__ short Asl[128 * 32];
    __shared__ short Bsl[128 * 32];
    int tid = threadIdx.x;
    int wave = tid >> 6, lane = tid & 63;
    int m0 = blockIdx.x * 128, n0 = blockIdx.y * 128;

    int lrow = lane >> 2;
    int cg   = lane & 3;
    int ss   = (lane >> 3) & 3;
    int gq   = (cg - ss) & 3;
    const short* Ab = (const short*)A;
    const short* Bb = (const short*)Bt;
    const short* gA0 = Ab + (size_t)(m0 + wave * 32 + lrow) * lda + gq * 8;
    const short* gA1 = gA0 + (size_t)16 * lda;
    const short* gB0 = Bb + (size_t)(n0 + wave * 32 + lrow) * Kdim + gq * 8;
    const short* gB1 = gB0 + (size_t)16 * Kdim;
    short* lA0 = &Asl[(wave * 32) * 32];
    short* lA1 = &Asl[(wave * 32 + 16) * 32];
    short* lB0 = &Bsl[(wave * 32) * 32];
    short* lB1 = &Bsl[(wave * 32 + 16) * 32];

    int wm = wave >> 1, wn = wave & 1;
    int rrow = lane & 15, quad = lane >> 4;
    int srd  = (rrow >> 1) & 3;

    f32x4 acc[4][4];
    #pragma unroll
    for (int i = 0; i < 4; ++i)
        #pragma unroll
        for (int j = 0; j < 4; ++j)
            acc[i][j] = (f32x4){0.f, 0.f, 0.f, 0.f};

    for (int k0 = 0; k0 < Kdim; k0 += 32) {
        __syncthreads();
        GLOAD_LDS16(gA0 + k0, lA0);
        GLOAD_LDS16(gA1 + k0, lA1);
        GLOAD_LDS16(gB0 + k0, lB0);
        GLOAD_LDS16(gB1 + k0, lB1);
        __syncthreads();
        short8 afr[4], bfr[4];
        #pragma unroll
        for (int mt = 0; mt < 4; ++mt) {
            int rowa = wm * 64 + mt * 16 + rrow;
            afr[mt] = *(const short8*)&Asl[rowa * 32 + ((quad + srd) & 3) * 8];
            int rowb = wn * 64 + mt * 16 + rrow;
            bfr[mt] = *(const short8*)&Bsl[rowb * 32 + ((quad + srd) & 3) * 8];
        }
        #pragma unroll
        for (int mt = 0; mt < 4; ++mt)
            #pragma unroll
            for (int nt = 0; nt < 4; ++nt)
                acc[mt][nt] = __builtin_amdgcn_mfma_f32_16x16x32_bf16(
                    afr[mt], bfr[nt], acc[mt][nt], 0, 0, 0);
    }

    #pragma unroll
    for (int mt = 0; mt < 4; ++mt) {
        #pragma unroll
        for (int nt = 0; nt < 4; ++nt) {
            int n = wn * 64 + nt * 16 + rrow;
            float bv = HASBIAS ? bias[n0 + n] : 0.f;
            #pragma unroll
            for (int i = 0; i < 4; ++i) {
                int m = m0 + wm * 64 + mt * 16 + quad * 4 + i;
                float v = acc[mt][nt][i] + bv;
                if (RELU) v = fmaxf(v, 0.f);
                size_t off = (size_t)m * ldc + coff + n0 + n;
                if (OUTBF16) ((__hip_bfloat16*)Cout)[off] = __float2bfloat16(v);
                else         ((float*)Cout)[off] = v;
            }
        }
    }
}

// ---------------------------------------------------------------------------
// Kernel 4: attention per (b,h). 4 threads/query row, 50-wide n-chunks,
// online softmax + 4-lane merge. Mask as bitmask (from knn) — no mask
// stream; masked n are SKIPPED (identical to the -inf path).
// ---------------------------------------------------------------------------
__global__ __launch_bounds__(832) void attn_kernel(
    const float* __restrict__ q, const __hip_bfloat16* __restrict__ kvf,
    const u64* __restrict__ maskbits, __hip_bfloat16* __restrict__ att)
{
    int b = blockIdx.x / Hc, h = blockIdx.x % Hc;
    __shared__ float4 sk[Nc][5];
    __shared__ float4 sv[Nc][5];
    __shared__ u64 smask[Nc][4];
    int t = threadIdx.x;

    for (int i = t; i < Nc * 4; i += 832) {
        int n = i >> 2, g = i & 3;
        const __hip_bfloat16* kr = kvf + ((size_t)b * Nc + n) * 256 + h * QKc + g * 4;
        const __hip_bfloat16* vr = kr + 128;
        sk[n][g] = make_float4(__bfloat162float(kr[0]), __bfloat162float(kr[1]),
                               __bfloat162float(kr[2]), __bfloat162float(kr[3]));
        sv[n][g] = make_float4(__bfloat162float(vr[0]), __bfloat162float(vr[1]),
                               __bfloat162float(vr[2]), __bfloat162float(vr[3]));
        smask[n][g] = maskbits[((size_t)b * Rc + n) * 4 + g];
    }
    __syncthreads();

    int r = t >> 2, c = t & 3;
    if (r < Rc) {
        float4 q0, q1, q2, q3;
        {
            const float* qrow = q + ((size_t)b * Rc + r) * 128 + h * QKc;
            q0 = *(const float4*)(qrow + 0);
            q1 = *(const float4*)(qrow + 4);
            q2 = *(const float4*)(qrow + 8);
            q3 = *(const float4*)(qrow + 12);
            q0.x *= 0.25f; q0.y *= 0.25f; q0.z *= 0.25f; q0.w *= 0.25f;
            q1.x *= 0.25f; q1.y *= 0.25f; q1.z *= 0.25f; q1.w *= 0.25f;
            q2.x *= 0.25f; q2.y *= 0.25f; q2.z *= 0.25f; q2.w *= 0.25f;
            q3.x *= 0.25f; q3.y *= 0.25f; q3.z *= 0.25f; q3.w *= 0.25f;
        }
        // 50-bit allowed-window for this thread's chunk [c*50, c*50+50)
        int base = c * 50;
        int wi = base >> 6, sh = base & 63;
        u64 lo = smask[r][wi];
        u64 win = (sh == 0) ? lo : ((lo >> sh) | (smask[r][wi + 1] << (64 - sh)));

        float m = -INFINITY, l = 0.f, o[QKc] = {};
        for (int i = 0; i < 50; ++i) {
            if (!((win >> i) & 1ull)) continue;
            int n = base + i;
            float4 k0 = sk[n][0], k1 = sk[n][1], k2 = sk[n][2], k3 = sk[n][3];
            float s = q0.x * k0.x + q0.y * k0.y + q0.z * k0.z + q0.w * k0.w
                    + q1.x * k1.x + q1.y * k1.y + q1.z * k1.z + q1.w * k1.w
                    + q2.x * k2.x + q2.y * k2.y + q2.z * k2.z + q2.w * k2.w
                    + q3.x * k3.x + q3.y * k3.y + q3.z * k3.z + q3.w * k3.w;
            float mnew = fmaxf(m, s);
            float alpha = expf(m - mnew);     // m=-inf,mnew finite -> 0
            float p = expf(s - mnew);
            l = l * alpha + p;
            float4 v0 = sv[n][0], v1 = sv[n][1], v2 = sv[n][2], v3 = sv[n][3];
            o[0]  = o[0]  * alpha + p * v0.x;  o[1]  = o[1]  * alpha + p * v0.y;
            o[2]  = o[2]  * alpha + p * v0.z;  o[3]  = o[3]  * alpha + p * v0.w;
            o[4]  = o[4]  * alpha + p * v1.x;  o[5]  = o[5]  * alpha + p * v1.y;
            o[6]  = o[6]  * alpha + p * v1.z;  o[7]  = o[7]  * alpha + p * v1.w;
            o[8]  = o[8]  * alpha + p * v2.x;  o[9]  = o[9]  * alpha + p * v2.y;
            o[10] = o[10] * alpha + p * v2.z;  o[11] = o[11] * alpha + p * v2.w;
            o[12] = o[12] * alpha + p * v3.x;  o[13] = o[13] * alpha + p * v3.y;
            o[14] = o[14] * alpha + p * v3.z;  o[15] = o[15] * alpha + p * v3.w;
            m = mnew;
        }
        float M = m;
        M = fmaxf(M, __shfl_xor(M, 1));
        M = fmaxf(M, __shfl_xor(M, 2));
        float sc = (m == -INFINITY) ? 0.f : expf(m - M);
        l *= sc;
        l += __shfl_xor(l, 1);
        l += __shfl_xor(l, 2);
        #pragma unroll
        for (int j = 0; j < QKc; ++j) {
            float oj = o[j] * sc;
            oj += __shfl_xor(oj, 1);
            oj += __shfl_xor(oj, 2);
            o[j] = oj;
        }
        if (c == 0) {
            float inv = (l > 0.f) ? 1.f / l : 0.f;
            __hip_bfloat16* arow = att + ((size_t)b * Rc + r) * 128 + h * QKc;
            #pragma unroll
            for (int j = 0; j < QKc; ++j) arow[j] = __float2bfloat16(o[j] * inv);
        }
    }
}

// ---------------------------------------------------------------------------
// Kernel 5: logits = 10*tanh((mh @ enc^T)/sqrt(128)) + mask -> d_out.
// bf16 MFMA, per-batch 128x128 tiles, K=128. mh/encb padded allocations so
// row staging past r=200 of the last batch stays in-bounds (masked at write).
// ---------------------------------------------------------------------------
__global__ __launch_bounds__(256) void logits_mfma_kernel(
    const __hip_bfloat16* __restrict__ mh, const __hip_bfloat16* __restrict__ encb,
    const float* __restrict__ mask, float* __restrict__ out)
{
    __shared__ short Asl[128 * 32];
    __shared__ short Bsl[128 * 32];
    int b = blockIdx.x;
    int m0 = blockIdx.y * 128;   // query-row tile within batch
    int n0 = blockIdx.z * 128;   // node tile within batch
    int tid = threadIdx.x;
    int wave = tid >> 6, lane = tid & 63;

    int lrow = lane >> 2;
    int cg   = lane & 3;
    int ss   = (lane >> 3) & 3;
    int gq   = (cg - ss) & 3;
    const short* Ab = (const short*)(mh + (size_t)b * Rc * 128);
    const short* Bb = (const short*)(encb + (size_t)b * Nc * 128);
    const short* gA0 = Ab + (size_t)(m0 + wave * 32 + lrow) * 128 + gq * 8;
    const short* gA1 = gA0 + (size_t)16 * 128;
    const short* gB0 = Bb + (size_t)(n0 + wave * 32 + lrow) * 128 + gq * 8;
    const short* gB1 = gB0 + (size_t)16 * 128;
    short* lA0 = &Asl[(wave * 32) * 32];
    short* lA1 = &Asl[(wave * 32 + 16) * 32];
    short* lB0 = &Bsl[(wave * 32) * 32];
    short* lB1 = &Bsl[(wave * 32 + 16) * 32];

    int wm = wave >> 1, wn = wave & 1;
    int rrow = lane & 15, quad = lane >> 4;
    int srd  = (rrow >> 1) & 3;

    f32x4 acc[4][4];
    #pragma unroll
    for (int i = 0; i < 4; ++i)
        #pragma unroll
        for (int j = 0; j < 4; ++j)
            acc[i][j] = (f32x4){0.f, 0.f, 0.f, 0.f};

    for (int k0 = 0; k0 < 128; k0 += 32) {
        __syncthreads();
        GLOAD_LDS16(gA0 + k0, lA0);
        GLOAD_LDS16(gA1 + k0, lA1);
        GLOAD_LDS16(gB0 + k0, lB0);
        GLOAD_LDS16(gB1 + k0, lB1);
        __syncthreads();
        short8 afr[4], bfr[4];
        #pragma unroll
        for (int mt = 0; mt < 4; ++mt) {
            int rowa = wm * 64 + mt * 16 + rrow;
            afr[mt] = *(const short8*)&Asl[rowa * 32 + ((quad + srd) & 3) * 8];
            int rowb = wn * 64 + mt * 16 + rrow;
            bfr[mt] = *(const short8*)&Bsl[rowb * 32 + ((quad + srd) & 3) * 8];
        }
        #pragma unroll
        for (int mt = 0; mt < 4; ++mt)
            #pragma unroll
            for (int nt = 0; nt < 4; ++nt)
                acc[mt][nt] = __builtin_amdgcn_mfma_f32_16x16x32_bf16(
                    afr[mt], bfr[nt], acc[mt][nt], 0, 0, 0);
    }

    const float scale = 0.08838834764831843f;  // 1/sqrt(128)
    #pragma unroll
    for (int mt = 0; mt < 4; ++mt) {
        #pragma unroll
        for (int nt = 0; nt < 4; ++nt) {
            int n = n0 + wn * 64 + nt * 16 + rrow;
            #pragma unroll
            for (int i = 0; i < 4; ++i) {
                int r = m0 + wm * 64 + mt * 16 + quad * 4 + i;
                if (r < Rc && n < Nc) {
                    size_t off = ((size_t)b * Rc + r) * Nc + n;
                    out[off] = 10.f * tanhf(acc[mt][nt][i] * scale) + mask[off];
                }
            }
        }
    }
}

// ---------------------------------------------------------------------------
// Kernel 6: row softmax over N=200, in place.
// ---------------------------------------------------------------------------
__global__ __launch_bounds__(64) void softmax_kernel(float* __restrict__ out)
{
    int br = blockIdx.x;
    float* row = out + (size_t)br * Nc;
    int t = threadIdx.x;
    float v[4]; float m = -INFINITY;
    #pragma unroll
    for (int j = 0; j < 4; ++j) {
        int n = t + 64 * j;
        v[j] = (n < Nc) ? row[n] : -INFINITY;
        m = fmaxf(m, v[j]);
    }
    #pragma unroll
    for (int off = 32; off > 0; off >>= 1) m = fmaxf(m, __shfl_xor(m, off));
    float e[4]; float s = 0.f;
    #pragma unroll
    for (int j = 0; j < 4; ++j) {
        e[j] = (v[j] == -INFINITY) ? 0.f : expf(v[j] - m);
        s += e[j];
    }
    #pragma unroll
    for (int off = 32; off > 0; off >>= 1) s += __shfl_xor(s, off);
    float inv = 1.f / s;
    #pragma unroll
    for (int j = 0; j < 4; ++j) {
        int n = t + 64 * j;
        if (n < Nc) row[n] = e[j] * inv;
    }
}

// ---------------------------------------------------------------------------
extern "C" void kernel_launch(void* const* d_in, const int* in_sizes, int n_in,
                              void* d_out, int out_size, void* d_ws, size_t ws_size,
                              hipStream_t stream)
{
    const float* enc  = (const float*)d_in[0];
    const float* dist = (const float*)d_in[1];
    const float* mask = (const float*)d_in[2];
    const int*   cur  = (const int*)d_in[3];
    const float* Wq   = (const float*)d_in[4];
    const float* Wk   = (const float*)d_in[5];
    const float* Wv   = (const float*)d_in[6];
    const float* Wmhc = (const float*)d_in[7];
    const float* bmhc = (const float*)d_in[8];
    const float* W1   = (const float*)d_in[9];
    const float* b1   = (const float*)d_in[10];
    const float* W2   = (const float*)d_in[11];
    const float* b2   = (const float*)d_in[12];
    float* out = (float*)d_out;

    char* ws = (char*)d_ws;
    size_t off = 0;
    auto alloc = [&](size_t bytes) { char* p = ws + off; off += (bytes + 255) & ~(size_t)255; return p; };
    __hip_bfloat16* W1t  = (__hip_bfloat16*)alloc((size_t)640 * 1280 * 2);
    __hip_bfloat16* Wkvt = (__hip_bfloat16*)alloc((size_t)256 * 128 * 2);
    __hip_bfloat16* Wmt  = (__hip_bfloat16*)alloc((size_t)128 * 128 * 2);
    __hip_bfloat16* Wcat = (__hip_bfloat16*)alloc((size_t)128 * 768 * 2);
    float* bq = (float*)alloc((size_t)128 * 4);
    __hip_bfloat16* encb = (__hip_bfloat16*)alloc((size_t)(Bc * Nc + 64) * Dc * 2);  // +64 rows pad
    __hip_bfloat16* bmat = (__hip_bfloat16*)alloc((size_t)BRc * 1280 * 2);
    __hip_bfloat16* hq   = (__hip_bfloat16*)alloc((size_t)BRc * 768 * 2);
    float* q   = (float*)alloc((size_t)BRc * 128 * 4);
    __hip_bfloat16* kvf = (__hip_bfloat16*)alloc((size_t)Bc * Nc * 256 * 2);
    __hip_bfloat16* att = (__hip_bfloat16*)alloc((size_t)BRc * 128 * 2);
    __hip_bfloat16* mh  = (__hip_bfloat16*)alloc((size_t)(BRc + 64) * 128 * 2);      // +64 rows pad
    u64* maskbits = (u64*)alloc((size_t)BRc * 4 * 8);

    // 1) weight preprocessing
    prep_kernel<<<930, 256, 0, stream>>>(W1, W2, Wq, Wmhc, Wk, Wv, b2, enc,
                                         W1t, Wkvt, Wmt, Wcat, bq, encb);
    // 2) kNN select + gather + bitmask
    knn_gather_kernel<<<BRc, 128, 0, stream>>>(enc, dist, mask, cur, bmat, hq, maskbits);
    // 3) kvf = enc @ [Wk|Wv]
    mfma_gemm_kernel<false, false, true><<<dim3((Bc * Nc) / 128, 2), 256, 0, stream>>>(
        encb, 128, Wkvt, 128, nullptr, kvf, 256, 0);
    // 4) hq[:,128:768] = relu(bmat @ W1 + b1)
    mfma_gemm_kernel<true, true, true><<<dim3(BRc / 128, 640 / 128), 256, 0, stream>>>(
        bmat, 1280, W1t, 1280, b1, hq, 768, 128);
    // 5) q = hq @ Wcat^T + bq   (folds W2 & Wq)
    mfma_gemm_kernel<false, true, false><<<dim3(BRc / 128, 1), 256, 0, stream>>>(
        hq, 768, Wcat, 768, bq, q, 128, 0);
    // 6) attention
    attn_kernel<<<Bc * Hc, 832, 0, stream>>>(q, kvf, maskbits, att);
    // 7) mh = att @ Wmhc + b_mhc  (bf16 out for MFMA logits)
    mfma_gemm_kernel<false, true, true><<<dim3(BRc / 128, 1), 256, 0, stream>>>(
        att, 128, Wmt, 128, bmhc, mh, 128, 0);
    // 8) logits (MFMA) + tanh + mask
    logits_mfma_kernel<<<dim3(Bc, 2, 2), 256, 0, stream>>>(mh, encb, mask, out);
    // 9) softmax
    softmax_kernel<<<BRc, 64, 0, stream>>>(out);
}

// Round 6
// 266.968 us; speedup vs baseline: 1.0398x; 1.0200x over previous
//
#include <hip/hip_runtime.h>
#include <hip/hip_bf16.h>
#include <math.h>

#define Bc 32
#define Rc 200
#define Nc 200
#define Dc 128
#define Hc 8
#define QKc 16
#define Kc 10
#define BRc (Bc*Rc)

typedef __attribute__((ext_vector_type(8))) short short8;
typedef __attribute__((ext_vector_type(4))) float f32x4;
typedef unsigned long long u64;

#define GLOAD_LDS16(g, l) __builtin_amdgcn_global_load_lds( \
    (const __attribute__((address_space(1))) void*)(g), \
    (__attribute__((address_space(3))) void*)(l), 16, 0, 0)

// ---------------------------------------------------------------------------
// 32x32 transpose+convert tile helper (block-uniform call sites only)
// ---------------------------------------------------------------------------
__device__ inline void transpose_tile(const float* __restrict__ src, int lds_,
                                      __hip_bfloat16* __restrict__ dst, int ldd,
                                      int k0, int n0, float scale)
{
    __shared__ float tile[32][33];
    int tx = threadIdx.x & 31, ty = threadIdx.x >> 5;  // 32 x 8
    #pragma unroll
    for (int i = ty; i < 32; i += 8)
        tile[i][tx] = src[(size_t)(k0 + i) * lds_ + n0 + tx];
    __syncthreads();
    #pragma unroll
    for (int i = ty; i < 32; i += 8)
        dst[(size_t)(n0 + i) * ldd + k0 + tx] = __float2bfloat16(tile[tx][i] * scale);
}

// ---------------------------------------------------------------------------
// Kernel P: all weight preprocessing in ONE launch (role = blockIdx.x range).
// Wcat/bq carry the attention scale 0.25 folded in (q comes out pre-scaled).
// ---------------------------------------------------------------------------
__global__ __launch_bounds__(256) void prep_kernel(
    const float* __restrict__ W1, const float* __restrict__ W2,
    const float* __restrict__ Wq, const float* __restrict__ Wmhc,
    const float* __restrict__ Wk, const float* __restrict__ Wv,
    const float* __restrict__ b2, const float* __restrict__ enc,
    __hip_bfloat16* __restrict__ W1t, __hip_bfloat16* __restrict__ Wkvt,
    __hip_bfloat16* __restrict__ Wmt, __hip_bfloat16* __restrict__ Wcat,
    float* __restrict__ bq, __hip_bfloat16* __restrict__ encb)
{
    int bid = blockIdx.x;
    int t = threadIdx.x;
    if (bid < 800) {
        transpose_tile(W1, 640, W1t, 1280, (bid % 40) * 32, (bid / 40) * 32, 1.f);
    } else if (bid < 816) {
        int id = bid - 800;
        transpose_tile(Wk, 128, Wkvt, 128, (id & 3) * 32, (id >> 2) * 32, 1.f);
    } else if (bid < 832) {
        int id = bid - 816;
        transpose_tile(Wv, 128, Wkvt + 128 * 128, 128, (id & 3) * 32, (id >> 2) * 32, 1.f);
    } else if (bid < 848) {
        int id = bid - 832;
        transpose_tile(Wmhc, 128, Wmt, 128, (id & 3) * 32, (id >> 2) * 32, 1.f);
    } else if (bid < 864) {
        int id = bid - 848;
        transpose_tile(Wq, 128, Wcat, 768, (id & 3) * 32, (id >> 2) * 32, 0.25f);
    } else if (bid < 904) {
        int j0 = (bid - 864) * 16;
        int n = t & 127, half = t >> 7;
        #pragma unroll
        for (int jj = 0; jj < 8; ++jj) {
            int j = j0 + half * 8 + jj;
            float acc = 0.f;
            for (int k = 0; k < 128; ++k)
                acc = fmaf(W2[(size_t)j * 128 + k], Wq[(size_t)(128 + k) * 128 + n], acc);
            Wcat[(size_t)n * 768 + 128 + j] = __float2bfloat16(acc * 0.25f);
        }
    } else if (bid < 929) {
        size_t base = (size_t)(bid - 904) * 32768 + (size_t)t * 4;
        #pragma unroll 4
        for (int it = 0; it < 32; ++it) {
            size_t i = base + (size_t)it * 1024;
            float4 v = *(const float4*)(enc + i);
            encb[i + 0] = __float2bfloat16(v.x);
            encb[i + 1] = __float2bfloat16(v.y);
            encb[i + 2] = __float2bfloat16(v.z);
            encb[i + 3] = __float2bfloat16(v.w);
        }
    } else {
        if (t < 128) {
            float acc = 0.f;
            for (int k = 0; k < 128; ++k)
                acc = fmaf(b2[k], Wq[(size_t)(128 + k) * 128 + t], acc);
            bq[t] = acc * 0.25f;
        }
    }
}

// ---------------------------------------------------------------------------
// Kernel 1: kNN top-10 + gather + pad-mean -> bmat; cur_emb -> hq[:,0:128];
// also emits allowed-bitmask maskbits[br][4].
// ---------------------------------------------------------------------------
__global__ __launch_bounds__(128) void knn_gather_kernel(
    const float* __restrict__ enc, const float* __restrict__ dist,
    const float* __restrict__ mask, const int* __restrict__ cur,
    __hip_bfloat16* __restrict__ bmat, __hip_bfloat16* __restrict__ hq,
    u64* __restrict__ maskbits)
{
    int br = blockIdx.x;
    int b = br / Rc;
    int t = threadIdx.x;
    __shared__ int s_idx[Kc];
    __shared__ float s_part[2][Kc];
    __shared__ float s_row[Kc];

    int c = cur[br];
    const float* drow = dist + ((size_t)b * Nc + c) * Nc;
    const float* mrow = mask + (size_t)br * Nc;

    if (t < 64) {
        float v[4];
        #pragma unroll
        for (int j = 0; j < 4; ++j) {
            int n = t + 64 * j;
            bool allowed = false;
            float val = INFINITY;
            if (n < Nc) {
                float mv = mrow[n];
                if (!isinf(mv)) { val = drow[n]; allowed = true; }
            }
            v[j] = val;
            u64 w = __ballot(allowed);
            if (t == 0) maskbits[(size_t)br * 4 + j] = w;
        }
        for (int k = 0; k < Kc; ++k) {
            float bv = v[0]; int bn = t;
            #pragma unroll
            for (int j = 1; j < 4; ++j) {
                if (v[j] < bv) { bv = v[j]; bn = t + 64 * j; }
            }
            #pragma unroll
            for (int off = 32; off > 0; off >>= 1) {
                float ov = __shfl_xor(bv, off);
                int   on = __shfl_xor(bn, off);
                if (ov < bv || (ov == bv && on < bn)) { bv = ov; bn = on; }
            }
            if (t == 0) s_idx[k] = isinf(bv) ? Nc : bn;
            int oj = bn >> 6, ol = bn & 63;
            if (t == ol) v[oj] = INFINITY;
        }
    }
    __syncthreads();

    float col[Kc]; float colsum = 0.f;
    #pragma unroll
    for (int k = 0; k < Kc; ++k) {
        int idx = s_idx[k];
        float val = 0.f;
        if (idx < Nc) val = enc[((size_t)b * Nc + idx) * Dc + t];
        col[k] = val; colsum += val;
    }
    int wave = t >> 6, lane = t & 63;
    #pragma unroll
    for (int k = 0; k < Kc; ++k) {
        float sv = col[k];
        #pragma unroll
        for (int off = 32; off > 0; off >>= 1) sv += __shfl_xor(sv, off);
        if (lane == 0) s_part[wave][k] = sv;
    }
    __syncthreads();
    if (t < Kc) s_row[t] = s_part[0][t] + s_part[1][t];
    __syncthreads();

    float cnt = 0.f;
    #pragma unroll
    for (int k = 0; k < Kc; ++k) cnt += (s_row[k] != 0.f) ? 1.f : 0.f;
    float mean = colsum / fmaxf(cnt, 1e-9f);

    __hip_bfloat16* brow = bmat + (size_t)br * (Kc * Dc);
    #pragma unroll
    for (int k = 0; k < Kc; ++k)
        brow[k * Dc + t] = __float2bfloat16((s_row[k] == 0.f) ? mean : col[k]);

    hq[(size_t)br * 768 + t] = __float2bfloat16(enc[((size_t)b * Nc + c) * Dc + t]);
}

// ---------------------------------------------------------------------------
// Kernel 3: bf16 MFMA GEMM. C = (relu)(A @ Bt^T + bias).
// ---------------------------------------------------------------------------
template<bool RELU, bool HASBIAS, bool OUTBF16>
__global__ __launch_bounds__(256) void mfma_gemm_kernel(
    const __hip_bfloat16* __restrict__ A, int lda,
    const __hip_bfloat16* __restrict__ Bt, int Kdim,
    const float* __restrict__ bias,
    void* __restrict__ Cout, int ldc, int coff)
{
    __shared__ short Asl[128 * 32];
    __shared__ short Bsl[128 * 32];
    int tid = threadIdx.x;
    int wave = tid >> 6, lane = tid & 63;
    int m0 = blockIdx.x * 128, n0 = blockIdx.y * 128;

    int lrow = lane >> 2;
    int cg   = lane & 3;
    int ss   = (lane >> 3) & 3;
    int gq   = (cg - ss) & 3;
    const short* Ab = (const short*)A;
    const short* Bb = (const short*)Bt;
    const short* gA0 = Ab + (size_t)(m0 + wave * 32 + lrow) * lda + gq * 8;
    const short* gA1 = gA0 + (size_t)16 * lda;
    const short* gB0 = Bb + (size_t)(n0 + wave * 32 + lrow) * Kdim + gq * 8;
    const short* gB1 = gB0 + (size_t)16 * Kdim;
    short* lA0 = &Asl[(wave * 32) * 32];
    short* lA1 = &Asl[(wave * 32 + 16) * 32];
    short* lB0 = &Bsl[(wave * 32) * 32];
    short* lB1 = &Bsl[(wave * 32 + 16) * 32];

    int wm = wave >> 1, wn = wave & 1;
    int rrow = lane & 15, quad = lane >> 4;
    int srd  = (rrow >> 1) & 3;

    f32x4 acc[4][4];
    #pragma unroll
    for (int i = 0; i < 4; ++i)
        #pragma unroll
        for (int j = 0; j < 4; ++j)
            acc[i][j] = (f32x4){0.f, 0.f, 0.f, 0.f};

    for (int k0 = 0; k0 < Kdim; k0 += 32) {
        __syncthreads();
        GLOAD_LDS16(gA0 + k0, lA0);
        GLOAD_LDS16(gA1 + k0, lA1);
        GLOAD_LDS16(gB0 + k0, lB0);
        GLOAD_LDS16(gB1 + k0, lB1);
        __syncthreads();
        short8 afr[4], bfr[4];
        #pragma unroll
        for (int mt = 0; mt < 4; ++mt) {
            int rowa = wm * 64 + mt * 16 + rrow;
            afr[mt] = *(const short8*)&Asl[rowa * 32 + ((quad + srd) & 3) * 8];
            int rowb = wn * 64 + mt * 16 + rrow;
            bfr[mt] = *(const short8*)&Bsl[rowb * 32 + ((quad + srd) & 3) * 8];
        }
        #pragma unroll
        for (int mt = 0; mt < 4; ++mt)
            #pragma unroll
            for (int nt = 0; nt < 4; ++nt)
                acc[mt][nt] = __builtin_amdgcn_mfma_f32_16x16x32_bf16(
                    afr[mt], bfr[nt], acc[mt][nt], 0, 0, 0);
    }

    #pragma unroll
    for (int mt = 0; mt < 4; ++mt) {
        #pragma unroll
        for (int nt = 0; nt < 4; ++nt) {
            int n = wn * 64 + nt * 16 + rrow;
            float bv = HASBIAS ? bias[n0 + n] : 0.f;
            #pragma unroll
            for (int i = 0; i < 4; ++i) {
                int m = m0 + wm * 64 + mt * 16 + quad * 4 + i;
                float v = acc[mt][nt][i] + bv;
                if (RELU) v = fmaxf(v, 0.f);
                size_t off = (size_t)m * ldc + coff + n0 + n;
                if (OUTBF16) ((__hip_bfloat16*)Cout)[off] = __float2bfloat16(v);
                else         ((float*)Cout)[off] = v;
            }
        }
    }
}

// ---------------------------------------------------------------------------
// Kernel 4: MFMA flash attention, one block per (b,h), 4 waves.
// Q pre-scaled (0.25 folded into Wcat/bq). 16x16x32 MFMA; K-dim padded
// 16->32 with zeros. V transposed in LDS for B-operand reads. Mask from
// maskbits, applied in registers. P routed through per-wave LDS strip to
// A-layout for PV. Rows padded 200->208 (pad rows: Q=0, mask=all-ones).
// ---------------------------------------------------------------------------
__global__ __launch_bounds__(256) void attn_mfma_kernel(
    const __hip_bfloat16* __restrict__ q, const __hip_bfloat16* __restrict__ kvf,
    const u64* __restrict__ maskbits, __hip_bfloat16* __restrict__ att)
{
    constexpr int RP = 208;      // padded rows / cols
    constexpr int QS = 40;       // Qs/Ks row stride in shorts (80 B, 16B-aligned)
    constexpr int VS = 232;      // Vt/Ps row stride in shorts (464 B, 16B-aligned)
    __shared__ short Qs[RP * QS];
    __shared__ short Ks[RP * QS];
    __shared__ short Vt[16 * VS];
    __shared__ short Ps[4][16 * VS];
    __shared__ u64 smask[RP][4];

    int b = blockIdx.x >> 3, h = blockIdx.x & 7;
    int t = threadIdx.x;
    int wave = t >> 6, lane = t & 63;
    int rrow = lane & 15, quad = lane >> 4;

    // ---- stage Q, K (zero pad cols 16..31 and rows >= 200)
    const short8 z8 = {0, 0, 0, 0, 0, 0, 0, 0};
    for (int idx = t; idx < RP * 2; idx += 256) {
        int r = idx >> 1, g = idx & 1;
        short8 qa = z8, ka = z8;
        if (r < Rc) {
            qa = *(const short8*)((const short*)q + ((size_t)(b * Rc + r)) * 128 + h * 16 + g * 8);
            ka = *(const short8*)((const short*)kvf + ((size_t)(b * Nc + r)) * 256 + h * 16 + g * 8);
        }
        *(short8*)&Qs[r * QS + g * 8] = qa;
        *(short8*)&Ks[r * QS + g * 8] = ka;
        *(short8*)&Qs[r * QS + 16 + g * 8] = z8;
        *(short8*)&Ks[r * QS + 16 + g * 8] = z8;
    }
    // ---- stage V transposed: Vt[d][n]
    if (t < Rc) {
        const short* vp = (const short*)kvf + ((size_t)(b * Nc + t)) * 256 + 128 + h * 16;
        short8 v0 = *(const short8*)vp;
        short8 v1 = *(const short8*)(vp + 8);
        #pragma unroll
        for (int d = 0; d < 8; ++d) Vt[d * VS + t] = v0[d];
        #pragma unroll
        for (int d = 0; d < 8; ++d) Vt[(d + 8) * VS + t] = v1[d];
    }
    // zero Vt cols [200, 232)
    for (int idx = t; idx < 16 * 32; idx += 256) {
        int d = idx >> 5, cN = 200 + (idx & 31);
        if (cN < VS) Vt[d * VS + cN] = 0;
    }
    // zero Ps pad cols [208, 224) for this wave's strip
    for (int idx = lane; idx < 16 * 16; idx += 64) {
        int rr = idx >> 4, cc = 208 + (idx & 15);
        Ps[wave][rr * VS + cc] = 0;
    }
    // stage mask bits (pad rows all-allowed)
    for (int idx = t; idx < RP * 4; idx += 256) {
        int r = idx >> 2, w = idx & 3;
        smask[r][w] = (r < Rc) ? maskbits[((size_t)b * Rc + r) * 4 + w] : ~0ull;
    }
    __syncthreads();

    for (int rt = wave; rt < 13; rt += 4) {
        // Q A-fragment for this row tile (lane: m=rrow, k=quad*8+j)
        short8 qf = *(const short8*)&Qs[(rt * 16 + rrow) * QS + quad * 8];
        f32x4 sacc[13];
        #pragma unroll
        for (int nt = 0; nt < 13; ++nt) {
            short8 kf = *(const short8*)&Ks[(nt * 16 + rrow) * QS + quad * 8];
            sacc[nt] = __builtin_amdgcn_mfma_f32_16x16x32_bf16(
                qf, kf, (f32x4){0.f, 0.f, 0.f, 0.f}, 0, 0, 0);
        }
        // mask + softmax. Lane holds rows quad*4+i (i=0..3), col rrow per nt.
        float inv[4];
        #pragma unroll
        for (int i = 0; i < 4; ++i) {
            int r = rt * 16 + quad * 4 + i;
            u64 wv0 = smask[r][0], wv1 = smask[r][1], wv2 = smask[r][2], wv3 = smask[r][3];
            float mx = -INFINITY;
            #pragma unroll
            for (int nt = 0; nt < 13; ++nt) {
                u64 w = (nt < 4) ? wv0 : (nt < 8) ? wv1 : (nt < 12) ? wv2 : wv3;
                int sh = ((nt & 3) << 4) + rrow;
                float s = ((w >> sh) & 1ull) ? sacc[nt][i] : -INFINITY;
                sacc[nt][i] = s;
                mx = fmaxf(mx, s);
            }
            mx = fmaxf(mx, __shfl_xor(mx, 1));
            mx = fmaxf(mx, __shfl_xor(mx, 2));
            mx = fmaxf(mx, __shfl_xor(mx, 4));
            mx = fmaxf(mx, __shfl_xor(mx, 8));
            float l = 0.f;
            #pragma unroll
            for (int nt = 0; nt < 13; ++nt) {
                float p = __expf(sacc[nt][i] - mx);  // exp(-inf - m) = 0
                sacc[nt][i] = p;
                l += p;
            }
            l += __shfl_xor(l, 1);
            l += __shfl_xor(l, 2);
            l += __shfl_xor(l, 4);
            l += __shfl_xor(l, 8);
            inv[i] = (l > 0.f) ? 1.f / l : 0.f;
        }
        // write unnormalized P (bf16) to this wave's strip
        #pragma unroll
        for (int nt = 0; nt < 13; ++nt)
            #pragma unroll
            for (int i = 0; i < 4; ++i)
                *(__hip_bfloat16*)&Ps[wave][(quad * 4 + i) * VS + nt * 16 + rrow] =
                    __float2bfloat16(sacc[nt][i]);
        // PV: O[16 x 16] accumulated over 7 k-tiles of 32
        f32x4 oacc = (f32x4){0.f, 0.f, 0.f, 0.f};
        #pragma unroll
        for (int kt = 0; kt < 7; ++kt) {
            short8 pf = *(const short8*)&Ps[wave][rrow * VS + kt * 32 + quad * 8];
            short8 vf = *(const short8*)&Vt[rrow * VS + kt * 32 + quad * 8];
            oacc = __builtin_amdgcn_mfma_f32_16x16x32_bf16(pf, vf, oacc, 0, 0, 0);
        }
        // store (C layout: col d = rrow, row = quad*4+i), normalize by 1/l
        #pragma unroll
        for (int i = 0; i < 4; ++i) {
            int r = rt * 16 + quad * 4 + i;
            if (r < Rc)
                att[((size_t)(b * Rc + r)) * 128 + h * 16 + rrow] =
                    __float2bfloat16(oacc[i] * inv[i]);
        }
    }
}

// ---------------------------------------------------------------------------
// Kernel 5: logits = 10*tanh((mh @ enc^T)/sqrt(128)) + mask -> d_out.
// ---------------------------------------------------------------------------
__global__ __launch_bounds__(256) void logits_mfma_kernel(
    const __hip_bfloat16* __restrict__ mh, const __hip_bfloat16* __restrict__ encb,
    const float* __restrict__ mask, float* __restrict__ out)
{
    __shared__ short Asl[128 * 32];
    __shared__ short Bsl[128 * 32];
    int b = blockIdx.x;
    int m0 = blockIdx.y * 128;
    int n0 = blockIdx.z * 128;
    int tid = threadIdx.x;
    int wave = tid >> 6, lane = tid & 63;

    int lrow = lane >> 2;
    int cg   = lane & 3;
    int ss   = (lane >> 3) & 3;
    int gq   = (cg - ss) & 3;
    const short* Ab = (const short*)(mh + (size_t)b * Rc * 128);
    const short* Bb = (const short*)(encb + (size_t)b * Nc * 128);
    const short* gA0 = Ab + (size_t)(m0 + wave * 32 + lrow) * 128 + gq * 8;
    const short* gA1 = gA0 + (size_t)16 * 128;
    const short* gB0 = Bb + (size_t)(n0 + wave * 32 + lrow) * 128 + gq * 8;
    const short* gB1 = gB0 + (size_t)16 * 128;
    short* lA0 = &Asl[(wave * 32) * 32];
    short* lA1 = &Asl[(wave * 32 + 16) * 32];
    short* lB0 = &Bsl[(wave * 32) * 32];
    short* lB1 = &Bsl[(wave * 32 + 16) * 32];

    int wm = wave >> 1, wn = wave & 1;
    int rrow = lane & 15, quad = lane >> 4;
    int srd  = (rrow >> 1) & 3;

    f32x4 acc[4][4];
    #pragma unroll
    for (int i = 0; i < 4; ++i)
        #pragma unroll
        for (int j = 0; j < 4; ++j)
            acc[i][j] = (f32x4){0.f, 0.f, 0.f, 0.f};

    for (int k0 = 0; k0 < 128; k0 += 32) {
        __syncthreads();
        GLOAD_LDS16(gA0 + k0, lA0);
        GLOAD_LDS16(gA1 + k0, lA1);
        GLOAD_LDS16(gB0 + k0, lB0);
        GLOAD_LDS16(gB1 + k0, lB1);
        __syncthreads();
        short8 afr[4], bfr[4];
        #pragma unroll
        for (int mt = 0; mt < 4; ++mt) {
            int rowa = wm * 64 + mt * 16 + rrow;
            afr[mt] = *(const short8*)&Asl[rowa * 32 + ((quad + srd) & 3) * 8];
            int rowb = wn * 64 + mt * 16 + rrow;
            bfr[mt] = *(const short8*)&Bsl[rowb * 32 + ((quad + srd) & 3) * 8];
        }
        #pragma unroll
        for (int mt = 0; mt < 4; ++mt)
            #pragma unroll
            for (int nt = 0; nt < 4; ++nt)
                acc[mt][nt] = __builtin_amdgcn_mfma_f32_16x16x32_bf16(
                    afr[mt], bfr[nt], acc[mt][nt], 0, 0, 0);
    }

    const float scale = 0.08838834764831843f;  // 1/sqrt(128)
    #pragma unroll
    for (int mt = 0; mt < 4; ++mt) {
        #pragma unroll
        for (int nt = 0; nt < 4; ++nt) {
            int n = n0 + wn * 64 + nt * 16 + rrow;
            #pragma unroll
            for (int i = 0; i < 4; ++i) {
                int r = m0 + wm * 64 + mt * 16 + quad * 4 + i;
                if (r < Rc && n < Nc) {
                    size_t off = ((size_t)b * Rc + r) * Nc + n;
                    out[off] = 10.f * tanhf(acc[mt][nt][i] * scale) + mask[off];
                }
            }
        }
    }
}

// ---------------------------------------------------------------------------
// Kernel 6: row softmax over N=200, in place.
// ---------------------------------------------------------------------------
__global__ __launch_bounds__(64) void softmax_kernel(float* __restrict__ out)
{
    int br = blockIdx.x;
    float* row = out + (size_t)br * Nc;
    int t = threadIdx.x;
    float v[4]; float m = -INFINITY;
    #pragma unroll
    for (int j = 0; j < 4; ++j) {
        int n = t + 64 * j;
        v[j] = (n < Nc) ? row[n] : -INFINITY;
        m = fmaxf(m, v[j]);
    }
    #pragma unroll
    for (int off = 32; off > 0; off >>= 1) m = fmaxf(m, __shfl_xor(m, off));
    float e[4]; float s = 0.f;
    #pragma unroll
    for (int j = 0; j < 4; ++j) {
        e[j] = (v[j] == -INFINITY) ? 0.f : expf(v[j] - m);
        s += e[j];
    }
    #pragma unroll
    for (int off = 32; off > 0; off >>= 1) s += __shfl_xor(s, off);
    float inv = 1.f / s;
    #pragma unroll
    for (int j = 0; j < 4; ++j) {
        int n = t + 64 * j;
        if (n < Nc) row[n] = e[j] * inv;
    }
}

// ---------------------------------------------------------------------------
extern "C" void kernel_launch(void* const* d_in, const int* in_sizes, int n_in,
                              void* d_out, int out_size, void* d_ws, size_t ws_size,
                              hipStream_t stream)
{
    const float* enc  = (const float*)d_in[0];
    const float* dist = (const float*)d_in[1];
    const float* mask = (const float*)d_in[2];
    const int*   cur  = (const int*)d_in[3];
    const float* Wq   = (const float*)d_in[4];
    const float* Wk   = (const float*)d_in[5];
    const float* Wv   = (const float*)d_in[6];
    const float* Wmhc = (const float*)d_in[7];
    const float* bmhc = (const float*)d_in[8];
    const float* W1   = (const float*)d_in[9];
    const float* b1   = (const float*)d_in[10];
    const float* W2   = (const float*)d_in[11];
    const float* b2   = (const float*)d_in[12];
    float* out = (float*)d_out;

    char* ws = (char*)d_ws;
    size_t off = 0;
    auto alloc = [&](size_t bytes) { char* p = ws + off; off += (bytes + 255) & ~(size_t)255; return p; };
    __hip_bfloat16* W1t  = (__hip_bfloat16*)alloc((size_t)640 * 1280 * 2);
    __hip_bfloat16* Wkvt = (__hip_bfloat16*)alloc((size_t)256 * 128 * 2);
    __hip_bfloat16* Wmt  = (__hip_bfloat16*)alloc((size_t)128 * 128 * 2);
    __hip_bfloat16* Wcat = (__hip_bfloat16*)alloc((size_t)128 * 768 * 2);
    float* bq = (float*)alloc((size_t)128 * 4);
    __hip_bfloat16* encb = (__hip_bfloat16*)alloc((size_t)(Bc * Nc + 64) * Dc * 2);
    __hip_bfloat16* bmat = (__hip_bfloat16*)alloc((size_t)BRc * 1280 * 2);
    __hip_bfloat16* hq   = (__hip_bfloat16*)alloc((size_t)BRc * 768 * 2);
    __hip_bfloat16* q    = (__hip_bfloat16*)alloc((size_t)BRc * 128 * 2);
    __hip_bfloat16* kvf  = (__hip_bfloat16*)alloc((size_t)Bc * Nc * 256 * 2);
    __hip_bfloat16* att  = (__hip_bfloat16*)alloc((size_t)BRc * 128 * 2);
    __hip_bfloat16* mh   = (__hip_bfloat16*)alloc((size_t)(BRc + 64) * 128 * 2);
    u64* maskbits = (u64*)alloc((size_t)BRc * 4 * 8);

    // 1) weight preprocessing (Wcat/bq carry the 0.25 attention scale)
    prep_kernel<<<930, 256, 0, stream>>>(W1, W2, Wq, Wmhc, Wk, Wv, b2, enc,
                                         W1t, Wkvt, Wmt, Wcat, bq, encb);
    // 2) kNN select + gather + bitmask
    knn_gather_kernel<<<BRc, 128, 0, stream>>>(enc, dist, mask, cur, bmat, hq, maskbits);
    // 3) kvf = enc @ [Wk|Wv]
    mfma_gemm_kernel<false, false, true><<<dim3((Bc * Nc) / 128, 2), 256, 0, stream>>>(
        encb, 128, Wkvt, 128, nullptr, kvf, 256, 0);
    // 4) hq[:,128:768] = relu(bmat @ W1 + b1)
    mfma_gemm_kernel<true, true, true><<<dim3(BRc / 128, 640 / 128), 256, 0, stream>>>(
        bmat, 1280, W1t, 1280, b1, hq, 768, 128);
    // 5) q = (hq @ Wcat^T + bq)  [pre-scaled, bf16]
    mfma_gemm_kernel<false, true, true><<<dim3(BRc / 128, 1), 256, 0, stream>>>(
        hq, 768, Wcat, 768, bq, q, 128, 0);
    // 6) MFMA flash attention
    attn_mfma_kernel<<<Bc * Hc, 256, 0, stream>>>(q, kvf, maskbits, att);
    // 7) mh = att @ Wmhc + b_mhc (bf16 out)
    mfma_gemm_kernel<false, true, true><<<dim3(BRc / 128, 1), 256, 0, stream>>>(
        att, 128, Wmt, 128, bmhc, mh, 128, 0);
    // 8) logits (MFMA) + tanh + mask
    logits_mfma_kernel<<<dim3(Bc, 2, 2), 256, 0, stream>>>(mh, encb, mask, out);
    // 9) softmax
    softmax_kernel<<<BRc, 64, 0, stream>>>(out);
}

// Round 7
// 249.834 us; speedup vs baseline: 1.1112x; 1.0686x over previous
//
#include <hip/hip_runtime.h>
#include <hip/hip_bf16.h>
#include <math.h>

#define Bc 32
#define Rc 200
#define Nc 200
#define Dc 128
#define Hc 8
#define QKc 16
#define Kc 10
#define BRc (Bc*Rc)

typedef __attribute__((ext_vector_type(8))) short short8;
typedef __attribute__((ext_vector_type(4))) float f32x4;
typedef unsigned long long u64;

#define GLOAD_LDS16(g, l) __builtin_amdgcn_global_load_lds( \
    (const __attribute__((address_space(1))) void*)(g), \
    (__attribute__((address_space(3))) void*)(l), 16, 0, 0)

// ---------------------------------------------------------------------------
// 32x32 transpose+convert tile helper (block-uniform call sites only)
// ---------------------------------------------------------------------------
__device__ inline void transpose_tile(const float* __restrict__ src, int lds_,
                                      __hip_bfloat16* __restrict__ dst, int ldd,
                                      int k0, int n0, float scale)
{
    __shared__ float tile[32][33];
    int tx = threadIdx.x & 31, ty = threadIdx.x >> 5;  // 32 x 8
    #pragma unroll
    for (int i = ty; i < 32; i += 8)
        tile[i][tx] = src[(size_t)(k0 + i) * lds_ + n0 + tx];
    __syncthreads();
    #pragma unroll
    for (int i = ty; i < 32; i += 8)
        dst[(size_t)(n0 + i) * ldd + k0 + tx] = __float2bfloat16(tile[tx][i] * scale);
}

// ---------------------------------------------------------------------------
// Kernel P: all weight preprocessing in ONE launch (role = blockIdx.x range).
// Wcat/bq carry the attention scale 0.25 folded in (q comes out pre-scaled).
// ---------------------------------------------------------------------------
__global__ __launch_bounds__(256) void prep_kernel(
    const float* __restrict__ W1, const float* __restrict__ W2,
    const float* __restrict__ Wq, const float* __restrict__ Wmhc,
    const float* __restrict__ Wk, const float* __restrict__ Wv,
    const float* __restrict__ b2, const float* __restrict__ enc,
    __hip_bfloat16* __restrict__ W1t, __hip_bfloat16* __restrict__ Wkvt,
    __hip_bfloat16* __restrict__ Wmt, __hip_bfloat16* __restrict__ Wcat,
    float* __restrict__ bq, __hip_bfloat16* __restrict__ encb)
{
    int bid = blockIdx.x;
    int t = threadIdx.x;
    if (bid < 800) {
        transpose_tile(W1, 640, W1t, 1280, (bid % 40) * 32, (bid / 40) * 32, 1.f);
    } else if (bid < 816) {
        int id = bid - 800;
        transpose_tile(Wk, 128, Wkvt, 128, (id & 3) * 32, (id >> 2) * 32, 1.f);
    } else if (bid < 832) {
        int id = bid - 816;
        transpose_tile(Wv, 128, Wkvt + 128 * 128, 128, (id & 3) * 32, (id >> 2) * 32, 1.f);
    } else if (bid < 848) {
        int id = bid - 832;
        transpose_tile(Wmhc, 128, Wmt, 128, (id & 3) * 32, (id >> 2) * 32, 1.f);
    } else if (bid < 864) {
        int id = bid - 848;
        transpose_tile(Wq, 128, Wcat, 768, (id & 3) * 32, (id >> 2) * 32, 0.25f);
    } else if (bid < 904) {
        int j0 = (bid - 864) * 16;
        int n = t & 127, half = t >> 7;
        #pragma unroll
        for (int jj = 0; jj < 8; ++jj) {
            int j = j0 + half * 8 + jj;
            float acc = 0.f;
            for (int k = 0; k < 128; ++k)
                acc = fmaf(W2[(size_t)j * 128 + k], Wq[(size_t)(128 + k) * 128 + n], acc);
            Wcat[(size_t)n * 768 + 128 + j] = __float2bfloat16(acc * 0.25f);
        }
    } else if (bid < 929) {
        size_t base = (size_t)(bid - 904) * 32768 + (size_t)t * 4;
        #pragma unroll 4
        for (int it = 0; it < 32; ++it) {
            size_t i = base + (size_t)it * 1024;
            float4 v = *(const float4*)(enc + i);
            encb[i + 0] = __float2bfloat16(v.x);
            encb[i + 1] = __float2bfloat16(v.y);
            encb[i + 2] = __float2bfloat16(v.z);
            encb[i + 3] = __float2bfloat16(v.w);
        }
    } else {
        if (t < 128) {
            float acc = 0.f;
            for (int k = 0; k < 128; ++k)
                acc = fmaf(b2[k], Wq[(size_t)(128 + k) * 128 + t], acc);
            bq[t] = acc * 0.25f;
        }
    }
}

// ---------------------------------------------------------------------------
// Kernel 1: kNN top-10 + gather + pad-mean -> bmat; cur_emb -> hq[:,0:128];
// also emits allowed-bitmask maskbits[br][4].
// ---------------------------------------------------------------------------
__global__ __launch_bounds__(128) void knn_gather_kernel(
    const float* __restrict__ enc, const float* __restrict__ dist,
    const float* __restrict__ mask, const int* __restrict__ cur,
    __hip_bfloat16* __restrict__ bmat, __hip_bfloat16* __restrict__ hq,
    u64* __restrict__ maskbits)
{
    int br = blockIdx.x;
    int b = br / Rc;
    int t = threadIdx.x;
    __shared__ int s_idx[Kc];
    __shared__ float s_part[2][Kc];
    __shared__ float s_row[Kc];

    int c = cur[br];
    const float* drow = dist + ((size_t)b * Nc + c) * Nc;
    const float* mrow = mask + (size_t)br * Nc;

    if (t < 64) {
        float v[4];
        #pragma unroll
        for (int j = 0; j < 4; ++j) {
            int n = t + 64 * j;
            bool allowed = false;
            float val = INFINITY;
            if (n < Nc) {
                float mv = mrow[n];
                if (!isinf(mv)) { val = drow[n]; allowed = true; }
            }
            v[j] = val;
            u64 w = __ballot(allowed);
            if (t == 0) maskbits[(size_t)br * 4 + j] = w;
        }
        for (int k = 0; k < Kc; ++k) {
            float bv = v[0]; int bn = t;
            #pragma unroll
            for (int j = 1; j < 4; ++j) {
                if (v[j] < bv) { bv = v[j]; bn = t + 64 * j; }
            }
            #pragma unroll
            for (int off = 32; off > 0; off >>= 1) {
                float ov = __shfl_xor(bv, off);
                int   on = __shfl_xor(bn, off);
                if (ov < bv || (ov == bv && on < bn)) { bv = ov; bn = on; }
            }
            if (t == 0) s_idx[k] = isinf(bv) ? Nc : bn;
            int oj = bn >> 6, ol = bn & 63;
            if (t == ol) v[oj] = INFINITY;
        }
    }
    __syncthreads();

    float col[Kc]; float colsum = 0.f;
    #pragma unroll
    for (int k = 0; k < Kc; ++k) {
        int idx = s_idx[k];
        float val = 0.f;
        if (idx < Nc) val = enc[((size_t)b * Nc + idx) * Dc + t];
        col[k] = val; colsum += val;
    }
    int wave = t >> 6, lane = t & 63;
    #pragma unroll
    for (int k = 0; k < Kc; ++k) {
        float sv = col[k];
        #pragma unroll
        for (int off = 32; off > 0; off >>= 1) sv += __shfl_xor(sv, off);
        if (lane == 0) s_part[wave][k] = sv;
    }
    __syncthreads();
    if (t < Kc) s_row[t] = s_part[0][t] + s_part[1][t];
    __syncthreads();

    float cnt = 0.f;
    #pragma unroll
    for (int k = 0; k < Kc; ++k) cnt += (s_row[k] != 0.f) ? 1.f : 0.f;
    float mean = colsum / fmaxf(cnt, 1e-9f);

    __hip_bfloat16* brow = bmat + (size_t)br * (Kc * Dc);
    #pragma unroll
    for (int k = 0; k < Kc; ++k)
        brow[k * Dc + t] = __float2bfloat16((s_row[k] == 0.f) ? mean : col[k]);

    hq[(size_t)br * 768 + t] = __float2bfloat16(enc[((size_t)b * Nc + c) * Dc + t]);
}

// ---------------------------------------------------------------------------
// Kernel 3: bf16 MFMA GEMM. C = (relu)(A @ Bt^T + bias).
// BK=64 (two 32-k subtiles per barrier — halves barrier drains), grid
// x=n / y=m so consecutive blocks share the A-tile (L2 reuse).
// ---------------------------------------------------------------------------
template<bool RELU, bool HASBIAS, bool OUTBF16>
__global__ __launch_bounds__(256) void mfma_gemm_kernel(
    const __hip_bfloat16* __restrict__ A, int lda,
    const __hip_bfloat16* __restrict__ Bt, int Kdim,
    const float* __restrict__ bias,
    void* __restrict__ Cout, int ldc, int coff)
{
    __shared__ short Asl[2][128 * 32];
    __shared__ short Bsl[2][128 * 32];
    int tid = threadIdx.x;
    int wave = tid >> 6, lane = tid & 63;
    int m0 = blockIdx.y * 128, n0 = blockIdx.x * 128;   // y=m, x=n (A-tile reuse)

    int lrow = lane >> 2;
    int cg   = lane & 3;
    int ss   = (lane >> 3) & 3;
    int gq   = (cg - ss) & 3;
    const short* Ab = (const short*)A;
    const short* Bb = (const short*)Bt;
    const short* gA0 = Ab + (size_t)(m0 + wave * 32 + lrow) * lda + gq * 8;
    const short* gA1 = gA0 + (size_t)16 * lda;
    const short* gB0 = Bb + (size_t)(n0 + wave * 32 + lrow) * Kdim + gq * 8;
    const short* gB1 = gB0 + (size_t)16 * Kdim;

    int wm = wave >> 1, wn = wave & 1;
    int rrow = lane & 15, quad = lane >> 4;
    int srd  = (rrow >> 1) & 3;

    f32x4 acc[4][4];
    #pragma unroll
    for (int i = 0; i < 4; ++i)
        #pragma unroll
        for (int j = 0; j < 4; ++j)
            acc[i][j] = (f32x4){0.f, 0.f, 0.f, 0.f};

    for (int k0 = 0; k0 < Kdim; k0 += 64) {
        __syncthreads();
        #pragma unroll
        for (int s = 0; s < 2; ++s) {
            GLOAD_LDS16(gA0 + k0 + s * 32, &Asl[s][(wave * 32) * 32]);
            GLOAD_LDS16(gA1 + k0 + s * 32, &Asl[s][(wave * 32 + 16) * 32]);
            GLOAD_LDS16(gB0 + k0 + s * 32, &Bsl[s][(wave * 32) * 32]);
            GLOAD_LDS16(gB1 + k0 + s * 32, &Bsl[s][(wave * 32 + 16) * 32]);
        }
        __syncthreads();
        #pragma unroll
        for (int s = 0; s < 2; ++s) {
            short8 afr[4], bfr[4];
            #pragma unroll
            for (int mt = 0; mt < 4; ++mt) {
                int rowa = wm * 64 + mt * 16 + rrow;
                afr[mt] = *(const short8*)&Asl[s][rowa * 32 + ((quad + srd) & 3) * 8];
                int rowb = wn * 64 + mt * 16 + rrow;
                bfr[mt] = *(const short8*)&Bsl[s][rowb * 32 + ((quad + srd) & 3) * 8];
            }
            #pragma unroll
            for (int mt = 0; mt < 4; ++mt)
                #pragma unroll
                for (int nt = 0; nt < 4; ++nt)
                    acc[mt][nt] = __builtin_amdgcn_mfma_f32_16x16x32_bf16(
                        afr[mt], bfr[nt], acc[mt][nt], 0, 0, 0);
        }
    }

    #pragma unroll
    for (int mt = 0; mt < 4; ++mt) {
        #pragma unroll
        for (int nt = 0; nt < 4; ++nt) {
            int n = wn * 64 + nt * 16 + rrow;
            float bv = HASBIAS ? bias[n0 + n] : 0.f;
            #pragma unroll
            for (int i = 0; i < 4; ++i) {
                int m = m0 + wm * 64 + mt * 16 + quad * 4 + i;
                float v = acc[mt][nt][i] + bv;
                if (RELU) v = fmaxf(v, 0.f);
                size_t off = (size_t)m * ldc + coff + n0 + n;
                if (OUTBF16) ((__hip_bfloat16*)Cout)[off] = __float2bfloat16(v);
                else         ((float*)Cout)[off] = v;
            }
        }
    }
}

// ---------------------------------------------------------------------------
// Kernel 4: MFMA flash attention, one block per (b,h), 4 waves.
// ---------------------------------------------------------------------------
__global__ __launch_bounds__(256) void attn_mfma_kernel(
    const __hip_bfloat16* __restrict__ q, const __hip_bfloat16* __restrict__ kvf,
    const u64* __restrict__ maskbits, __hip_bfloat16* __restrict__ att)
{
    constexpr int RP = 208;
    constexpr int QS = 40;
    constexpr int VS = 232;
    __shared__ short Qs[RP * QS];
    __shared__ short Ks[RP * QS];
    __shared__ short Vt[16 * VS];
    __shared__ short Ps[4][16 * VS];
    __shared__ u64 smask[RP][4];

    int b = blockIdx.x >> 3, h = blockIdx.x & 7;
    int t = threadIdx.x;
    int wave = t >> 6, lane = t & 63;
    int rrow = lane & 15, quad = lane >> 4;

    const short8 z8 = {0, 0, 0, 0, 0, 0, 0, 0};
    for (int idx = t; idx < RP * 2; idx += 256) {
        int r = idx >> 1, g = idx & 1;
        short8 qa = z8, ka = z8;
        if (r < Rc) {
            qa = *(const short8*)((const short*)q + ((size_t)(b * Rc + r)) * 128 + h * 16 + g * 8);
            ka = *(const short8*)((const short*)kvf + ((size_t)(b * Nc + r)) * 256 + h * 16 + g * 8);
        }
        *(short8*)&Qs[r * QS + g * 8] = qa;
        *(short8*)&Ks[r * QS + g * 8] = ka;
        *(short8*)&Qs[r * QS + 16 + g * 8] = z8;
        *(short8*)&Ks[r * QS + 16 + g * 8] = z8;
    }
    if (t < Rc) {
        const short* vp = (const short*)kvf + ((size_t)(b * Nc + t)) * 256 + 128 + h * 16;
        short8 v0 = *(const short8*)vp;
        short8 v1 = *(const short8*)(vp + 8);
        #pragma unroll
        for (int d = 0; d < 8; ++d) Vt[d * VS + t] = v0[d];
        #pragma unroll
        for (int d = 0; d < 8; ++d) Vt[(d + 8) * VS + t] = v1[d];
    }
    for (int idx = t; idx < 16 * 32; idx += 256) {
        int d = idx >> 5, cN = 200 + (idx & 31);
        if (cN < VS) Vt[d * VS + cN] = 0;
    }
    for (int idx = lane; idx < 16 * 16; idx += 64) {
        int rr = idx >> 4, cc = 208 + (idx & 15);
        Ps[wave][rr * VS + cc] = 0;
    }
    for (int idx = t; idx < RP * 4; idx += 256) {
        int r = idx >> 2, w = idx & 3;
        smask[r][w] = (r < Rc) ? maskbits[((size_t)b * Rc + r) * 4 + w] : ~0ull;
    }
    __syncthreads();

    for (int rt = wave; rt < 13; rt += 4) {
        short8 qf = *(const short8*)&Qs[(rt * 16 + rrow) * QS + quad * 8];
        f32x4 sacc[13];
        #pragma unroll
        for (int nt = 0; nt < 13; ++nt) {
            short8 kf = *(const short8*)&Ks[(nt * 16 + rrow) * QS + quad * 8];
            sacc[nt] = __builtin_amdgcn_mfma_f32_16x16x32_bf16(
                qf, kf, (f32x4){0.f, 0.f, 0.f, 0.f}, 0, 0, 0);
        }
        float inv[4];
        #pragma unroll
        for (int i = 0; i < 4; ++i) {
            int r = rt * 16 + quad * 4 + i;
            u64 wv0 = smask[r][0], wv1 = smask[r][1], wv2 = smask[r][2], wv3 = smask[r][3];
            float mx = -INFINITY;
            #pragma unroll
            for (int nt = 0; nt < 13; ++nt) {
                u64 w = (nt < 4) ? wv0 : (nt < 8) ? wv1 : (nt < 12) ? wv2 : wv3;
                int sh = ((nt & 3) << 4) + rrow;
                float s = ((w >> sh) & 1ull) ? sacc[nt][i] : -INFINITY;
                sacc[nt][i] = s;
                mx = fmaxf(mx, s);
            }
            mx = fmaxf(mx, __shfl_xor(mx, 1));
            mx = fmaxf(mx, __shfl_xor(mx, 2));
            mx = fmaxf(mx, __shfl_xor(mx, 4));
            mx = fmaxf(mx, __shfl_xor(mx, 8));
            float l = 0.f;
            #pragma unroll
            for (int nt = 0; nt < 13; ++nt) {
                float p = __expf(sacc[nt][i] - mx);
                sacc[nt][i] = p;
                l += p;
            }
            l += __shfl_xor(l, 1);
            l += __shfl_xor(l, 2);
            l += __shfl_xor(l, 4);
            l += __shfl_xor(l, 8);
            inv[i] = (l > 0.f) ? 1.f / l : 0.f;
        }
        #pragma unroll
        for (int nt = 0; nt < 13; ++nt)
            #pragma unroll
            for (int i = 0; i < 4; ++i)
                *(__hip_bfloat16*)&Ps[wave][(quad * 4 + i) * VS + nt * 16 + rrow] =
                    __float2bfloat16(sacc[nt][i]);
        f32x4 oacc = (f32x4){0.f, 0.f, 0.f, 0.f};
        #pragma unroll
        for (int kt = 0; kt < 7; ++kt) {
            short8 pf = *(const short8*)&Ps[wave][rrow * VS + kt * 32 + quad * 8];
            short8 vf = *(const short8*)&Vt[rrow * VS + kt * 32 + quad * 8];
            oacc = __builtin_amdgcn_mfma_f32_16x16x32_bf16(pf, vf, oacc, 0, 0, 0);
        }
        #pragma unroll
        for (int i = 0; i < 4; ++i) {
            int r = rt * 16 + quad * 4 + i;
            if (r < Rc)
                att[((size_t)(b * Rc + r)) * 128 + h * 16 + rrow] =
                    __float2bfloat16(oacc[i] * inv[i]);
        }
    }
}

// ---------------------------------------------------------------------------
// Kernel 5: logits = 10*tanh((mh @ enc^T)/sqrt(128)) + mask -> d_out.
// ---------------------------------------------------------------------------
__global__ __launch_bounds__(256) void logits_mfma_kernel(
    const __hip_bfloat16* __restrict__ mh, const __hip_bfloat16* __restrict__ encb,
    const float* __restrict__ mask, float* __restrict__ out)
{
    __shared__ short Asl[128 * 32];
    __shared__ short Bsl[128 * 32];
    int b = blockIdx.x;
    int m0 = blockIdx.y * 128;
    int n0 = blockIdx.z * 128;
    int tid = threadIdx.x;
    int wave = tid >> 6, lane = tid & 63;

    int lrow = lane >> 2;
    int cg   = lane & 3;
    int ss   = (lane >> 3) & 3;
    int gq   = (cg - ss) & 3;
    const short* Ab = (const short*)(mh + (size_t)b * Rc * 128);
    const short* Bb = (const short*)(encb + (size_t)b * Nc * 128);
    const short* gA0 = Ab + (size_t)(m0 + wave * 32 + lrow) * 128 + gq * 8;
    const short* gA1 = gA0 + (size_t)16 * 128;
    const short* gB0 = Bb + (size_t)(n0 + wave * 32 + lrow) * 128 + gq * 8;
    const short* gB1 = gB0 + (size_t)16 * 128;
    short* lA0 = &Asl[(wave * 32) * 32];
    short* lA1 = &Asl[(wave * 32 + 16) * 32];
    short* lB0 = &Bsl[(wave * 32) * 32];
    short* lB1 = &Bsl[(wave * 32 + 16) * 32];

    int wm = wave >> 1, wn = wave & 1;
    int rrow = lane & 15, quad = lane >> 4;
    int srd  = (rrow >> 1) & 3;

    f32x4 acc[4][4];
    #pragma unroll
    for (int i = 0; i < 4; ++i)
        #pragma unroll
        for (int j = 0; j < 4; ++j)
            acc[i][j] = (f32x4){0.f, 0.f, 0.f, 0.f};

    for (int k0 = 0; k0 < 128; k0 += 32) {
        __syncthreads();
        GLOAD_LDS16(gA0 + k0, lA0);
        GLOAD_LDS16(gA1 + k0, lA1);
        GLOAD_LDS16(gB0 + k0, lB0);
        GLOAD_LDS16(gB1 + k0, lB1);
        __syncthreads();
        short8 afr[4], bfr[4];
        #pragma unroll
        for (int mt = 0; mt < 4; ++mt) {
            int rowa = wm * 64 + mt * 16 + rrow;
            afr[mt] = *(const short8*)&Asl[rowa * 32 + ((quad + srd) & 3) * 8];
            int rowb = wn * 64 + mt * 16 + rrow;
            bfr[mt] = *(const short8*)&Bsl[rowb * 32 + ((quad + srd) & 3) * 8];
        }
        #pragma unroll
        for (int mt = 0; mt < 4; ++mt)
            #pragma unroll
            for (int nt = 0; nt < 4; ++nt)
                acc[mt][nt] = __builtin_amdgcn_mfma_f32_16x16x32_bf16(
                    afr[mt], bfr[nt], acc[mt][nt], 0, 0, 0);
    }

    const float scale = 0.08838834764831843f;
    #pragma unroll
    for (int mt = 0; mt < 4; ++mt) {
        #pragma unroll
        for (int nt = 0; nt < 4; ++nt) {
            int n = n0 + wn * 64 + nt * 16 + rrow;
            #pragma unroll
            for (int i = 0; i < 4; ++i) {
                int r = m0 + wm * 64 + mt * 16 + quad * 4 + i;
                if (r < Rc && n < Nc) {
                    size_t off = ((size_t)b * Rc + r) * Nc + n;
                    out[off] = 10.f * tanhf(acc[mt][nt][i] * scale) + mask[off];
                }
            }
        }
    }
}

// ---------------------------------------------------------------------------
// Kernel 6: row softmax over N=200, in place.
// ---------------------------------------------------------------------------
__global__ __launch_bounds__(64) void softmax_kernel(float* __restrict__ out)
{
    int br = blockIdx.x;
    float* row = out + (size_t)br * Nc;
    int t = threadIdx.x;
    float v[4]; float m = -INFINITY;
    #pragma unroll
    for (int j = 0; j < 4; ++j) {
        int n = t + 64 * j;
        v[j] = (n < Nc) ? row[n] : -INFINITY;
        m = fmaxf(m, v[j]);
    }
    #pragma unroll
    for (int off = 32; off > 0; off >>= 1) m = fmaxf(m, __shfl_xor(m, off));
    float e[4]; float s = 0.f;
    #pragma unroll
    for (int j = 0; j < 4; ++j) {
        e[j] = (v[j] == -INFINITY) ? 0.f : expf(v[j] - m);
        s += e[j];
    }
    #pragma unroll
    for (int off = 32; off > 0; off >>= 1) s += __shfl_xor(s, off);
    float inv = 1.f / s;
    #pragma unroll
    for (int j = 0; j < 4; ++j) {
        int n = t + 64 * j;
        if (n < Nc) row[n] = e[j] * inv;
    }
}

// ---------------------------------------------------------------------------
extern "C" void kernel_launch(void* const* d_in, const int* in_sizes, int n_in,
                              void* d_out, int out_size, void* d_ws, size_t ws_size,
                              hipStream_t stream)
{
    const float* enc  = (const float*)d_in[0];
    const float* dist = (const float*)d_in[1];
    const float* mask = (const float*)d_in[2];
    const int*   cur  = (const int*)d_in[3];
    const float* Wq   = (const float*)d_in[4];
    const float* Wk   = (const float*)d_in[5];
    const float* Wv   = (const float*)d_in[6];
    const float* Wmhc = (const float*)d_in[7];
    const float* bmhc = (const float*)d_in[8];
    const float* W1   = (const float*)d_in[9];
    const float* b1   = (const float*)d_in[10];
    const float* W2   = (const float*)d_in[11];
    const float* b2   = (const float*)d_in[12];
    float* out = (float*)d_out;

    char* ws = (char*)d_ws;
    size_t off = 0;
    auto alloc = [&](size_t bytes) { char* p = ws + off; off += (bytes + 255) & ~(size_t)255; return p; };
    __hip_bfloat16* W1t  = (__hip_bfloat16*)alloc((size_t)640 * 1280 * 2);
    __hip_bfloat16* Wkvt = (__hip_bfloat16*)alloc((size_t)256 * 128 * 2);
    __hip_bfloat16* Wmt  = (__hip_bfloat16*)alloc((size_t)128 * 128 * 2);
    __hip_bfloat16* Wcat = (__hip_bfloat16*)alloc((size_t)128 * 768 * 2);
    float* bq = (float*)alloc((size_t)128 * 4);
    __hip_bfloat16* encb = (__hip_bfloat16*)alloc((size_t)(Bc * Nc + 64) * Dc * 2);
    __hip_bfloat16* bmat = (__hip_bfloat16*)alloc((size_t)BRc * 1280 * 2);
    __hip_bfloat16* hq   = (__hip_bfloat16*)alloc((size_t)BRc * 768 * 2);
    __hip_bfloat16* q    = (__hip_bfloat16*)alloc((size_t)BRc * 128 * 2);
    __hip_bfloat16* kvf  = (__hip_bfloat16*)alloc((size_t)Bc * Nc * 256 * 2);
    __hip_bfloat16* att  = (__hip_bfloat16*)alloc((size_t)BRc * 128 * 2);
    __hip_bfloat16* mh   = (__hip_bfloat16*)alloc((size_t)(BRc + 64) * 128 * 2);
    u64* maskbits = (u64*)alloc((size_t)BRc * 4 * 8);

    // 1) weight preprocessing (Wcat/bq carry the 0.25 attention scale)
    prep_kernel<<<930, 256, 0, stream>>>(W1, W2, Wq, Wmhc, Wk, Wv, b2, enc,
                                         W1t, Wkvt, Wmt, Wcat, bq, encb);
    // 2) kNN select + gather + bitmask
    knn_gather_kernel<<<BRc, 128, 0, stream>>>(enc, dist, mask, cur, bmat, hq, maskbits);
    // 3) kvf = enc @ [Wk|Wv]   (grid: x=n, y=m)
    mfma_gemm_kernel<false, false, true><<<dim3(2, (Bc * Nc) / 128), 256, 0, stream>>>(
        encb, 128, Wkvt, 128, nullptr, kvf, 256, 0);
    // 4) hq[:,128:768] = relu(bmat @ W1 + b1)
    mfma_gemm_kernel<true, true, true><<<dim3(640 / 128, BRc / 128), 256, 0, stream>>>(
        bmat, 1280, W1t, 1280, b1, hq, 768, 128);
    // 5) q = (hq @ Wcat^T + bq)  [pre-scaled, bf16]
    mfma_gemm_kernel<false, true, true><<<dim3(1, BRc / 128), 256, 0, stream>>>(
        hq, 768, Wcat, 768, bq, q, 128, 0);
    // 6) MFMA flash attention
    attn_mfma_kernel<<<Bc * Hc, 256, 0, stream>>>(q, kvf, maskbits, att);
    // 7) mh = att @ Wmhc + b_mhc (bf16 out)
    mfma_gemm_kernel<false, true, true><<<dim3(1, BRc / 128), 256, 0, stream>>>(
        att, 128, Wmt, 128, bmhc, mh, 128, 0);
    // 8) logits (MFMA) + tanh + mask
    logits_mfma_kernel<<<dim3(Bc, 2, 2), 256, 0, stream>>>(mh, encb, mask, out);
    // 9) softmax
    softmax_kernel<<<BRc, 64, 0, stream>>>(out);
}

// Round 8
// 235.057 us; speedup vs baseline: 1.1810x; 1.0629x over previous
//
#include <hip/hip_runtime.h>
#include <hip/hip_bf16.h>
#include <math.h>

#define Bc 32
#define Rc 200
#define Nc 200
#define Dc 128
#define Hc 8
#define QKc 16
#define Kc 10
#define BRc (Bc*Rc)

typedef __attribute__((ext_vector_type(8))) short short8;
typedef __attribute__((ext_vector_type(4))) float f32x4;
typedef unsigned long long u64;

#define GLOAD_LDS16(g, l) __builtin_amdgcn_global_load_lds( \
    (const __attribute__((address_space(1))) void*)(g), \
    (__attribute__((address_space(3))) void*)(l), 16, 0, 0)

// ---------------------------------------------------------------------------
// 32x32 transpose+convert tile helper (block-uniform call sites only)
// ---------------------------------------------------------------------------
__device__ inline void transpose_tile(const float* __restrict__ src, int lds_,
                                      __hip_bfloat16* __restrict__ dst, int ldd,
                                      int k0, int n0, float scale)
{
    __shared__ float tile[32][33];
    int tx = threadIdx.x & 31, ty = threadIdx.x >> 5;  // 32 x 8
    #pragma unroll
    for (int i = ty; i < 32; i += 8)
        tile[i][tx] = src[(size_t)(k0 + i) * lds_ + n0 + tx];
    __syncthreads();
    #pragma unroll
    for (int i = ty; i < 32; i += 8)
        dst[(size_t)(n0 + i) * ldd + k0 + tx] = __float2bfloat16(tile[tx][i] * scale);
}

// ---------------------------------------------------------------------------
// Kernel P: all weight preprocessing in ONE launch (role = blockIdx.x range).
// Wcat/bq carry the attention scale 0.25 folded in (q comes out pre-scaled).
// ---------------------------------------------------------------------------
__global__ __launch_bounds__(256) void prep_kernel(
    const float* __restrict__ W1, const float* __restrict__ W2,
    const float* __restrict__ Wq, const float* __restrict__ Wmhc,
    const float* __restrict__ Wk, const float* __restrict__ Wv,
    const float* __restrict__ b2, const float* __restrict__ enc,
    __hip_bfloat16* __restrict__ W1t, __hip_bfloat16* __restrict__ Wkvt,
    __hip_bfloat16* __restrict__ Wmt, __hip_bfloat16* __restrict__ Wcat,
    float* __restrict__ bq, __hip_bfloat16* __restrict__ encb)
{
    int bid = blockIdx.x;
    int t = threadIdx.x;
    if (bid < 800) {
        transpose_tile(W1, 640, W1t, 1280, (bid % 40) * 32, (bid / 40) * 32, 1.f);
    } else if (bid < 816) {
        int id = bid - 800;
        transpose_tile(Wk, 128, Wkvt, 128, (id & 3) * 32, (id >> 2) * 32, 1.f);
    } else if (bid < 832) {
        int id = bid - 816;
        transpose_tile(Wv, 128, Wkvt + 128 * 128, 128, (id & 3) * 32, (id >> 2) * 32, 1.f);
    } else if (bid < 848) {
        int id = bid - 832;
        transpose_tile(Wmhc, 128, Wmt, 128, (id & 3) * 32, (id >> 2) * 32, 1.f);
    } else if (bid < 864) {
        int id = bid - 848;
        transpose_tile(Wq, 128, Wcat, 768, (id & 3) * 32, (id >> 2) * 32, 0.25f);
    } else if (bid < 904) {
        int j0 = (bid - 864) * 16;
        int n = t & 127, half = t >> 7;
        #pragma unroll
        for (int jj = 0; jj < 8; ++jj) {
            int j = j0 + half * 8 + jj;
            float acc = 0.f;
            for (int k = 0; k < 128; ++k)
                acc = fmaf(W2[(size_t)j * 128 + k], Wq[(size_t)(128 + k) * 128 + n], acc);
            Wcat[(size_t)n * 768 + 128 + j] = __float2bfloat16(acc * 0.25f);
        }
    } else if (bid < 929) {
        size_t base = (size_t)(bid - 904) * 32768 + (size_t)t * 4;
        #pragma unroll 4
        for (int it = 0; it < 32; ++it) {
            size_t i = base + (size_t)it * 1024;
            float4 v = *(const float4*)(enc + i);
            encb[i + 0] = __float2bfloat16(v.x);
            encb[i + 1] = __float2bfloat16(v.y);
            encb[i + 2] = __float2bfloat16(v.z);
            encb[i + 3] = __float2bfloat16(v.w);
        }
    } else {
        if (t < 128) {
            float acc = 0.f;
            for (int k = 0; k < 128; ++k)
                acc = fmaf(b2[k], Wq[(size_t)(128 + k) * 128 + t], acc);
            bq[t] = acc * 0.25f;
        }
    }
}

// ---------------------------------------------------------------------------
// Kernel 1: kNN top-10 + pad-mean; writes per-row offset table aoff (gather
// directly consumed by gemm1), mean rows appended inside encb at row
// Bc*Nc+br; cur_emb -> hq[:,0:128]; allowed-bitmask maskbits[br][4].
// ---------------------------------------------------------------------------
__global__ __launch_bounds__(128) void knn_gather_kernel(
    const float* __restrict__ enc, const float* __restrict__ dist,
    const float* __restrict__ mask, const int* __restrict__ cur,
    __hip_bfloat16* __restrict__ encb, unsigned* __restrict__ aoff,
    __hip_bfloat16* __restrict__ hq, u64* __restrict__ maskbits)
{
    int br = blockIdx.x;
    int b = br / Rc;
    int t = threadIdx.x;
    __shared__ int s_idx[Kc];
    __shared__ float s_part[2][Kc];
    __shared__ float s_row[Kc];

    int c = cur[br];
    const float* drow = dist + ((size_t)b * Nc + c) * Nc;
    const float* mrow = mask + (size_t)br * Nc;

    if (t < 64) {
        float v[4];
        #pragma unroll
        for (int j = 0; j < 4; ++j) {
            int n = t + 64 * j;
            bool allowed = false;
            float val = INFINITY;
            if (n < Nc) {
                float mv = mrow[n];
                if (!isinf(mv)) { val = drow[n]; allowed = true; }
            }
            v[j] = val;
            u64 w = __ballot(allowed);
            if (t == 0) maskbits[(size_t)br * 4 + j] = w;
        }
        for (int k = 0; k < Kc; ++k) {
            float bv = v[0]; int bn = t;
            #pragma unroll
            for (int j = 1; j < 4; ++j) {
                if (v[j] < bv) { bv = v[j]; bn = t + 64 * j; }
            }
            #pragma unroll
            for (int off = 32; off > 0; off >>= 1) {
                float ov = __shfl_xor(bv, off);
                int   on = __shfl_xor(bn, off);
                if (ov < bv || (ov == bv && on < bn)) { bv = ov; bn = on; }
            }
            if (t == 0) s_idx[k] = isinf(bv) ? Nc : bn;
            int oj = bn >> 6, ol = bn & 63;
            if (t == ol) v[oj] = INFINITY;
        }
    }
    __syncthreads();

    float col[Kc]; float colsum = 0.f;
    #pragma unroll
    for (int k = 0; k < Kc; ++k) {
        int idx = s_idx[k];
        float val = 0.f;
        if (idx < Nc) val = enc[((size_t)b * Nc + idx) * Dc + t];
        col[k] = val; colsum += val;
    }
    int wave = t >> 6, lane = t & 63;
    #pragma unroll
    for (int k = 0; k < Kc; ++k) {
        float sv = col[k];
        #pragma unroll
        for (int off = 32; off > 0; off >>= 1) sv += __shfl_xor(sv, off);
        if (lane == 0) s_part[wave][k] = sv;
    }
    __syncthreads();
    if (t < Kc) s_row[t] = s_part[0][t] + s_part[1][t];
    __syncthreads();

    float cnt = 0.f;
    #pragma unroll
    for (int k = 0; k < Kc; ++k) cnt += (s_row[k] != 0.f) ? 1.f : 0.f;
    float mean = colsum / fmaxf(cnt, 1e-9f);

    // mean row into encb (row Bc*Nc + br)
    encb[((size_t)(Bc * Nc) + br) * Dc + t] = __float2bfloat16(mean);
    // offset table: element offset (shorts) of the source row for each slot
    if (t < Kc) {
        int idx = s_idx[t];
        unsigned row = (s_row[t] == 0.f) ? (unsigned)(Bc * Nc + br)
                                         : (unsigned)(b * Nc + idx);
        aoff[(size_t)br * 16 + t] = row << 7;
    }

    hq[(size_t)br * 768 + t] = __float2bfloat16(enc[((size_t)b * Nc + c) * Dc + t]);
}

// ---------------------------------------------------------------------------
// Kernel 2: GEMM1 hq[:,128:768] = relu(A @ W1t^T + b1) where A rows are
// GATHERED from encb via aoff (no materialized bmat). K=1280 fully unrolled;
// BK=64; per-lane gather addresses into global_load_lds.
// ---------------------------------------------------------------------------
__global__ __launch_bounds__(256) void gemm1_kernel(
    const __hip_bfloat16* __restrict__ encb, const unsigned* __restrict__ aoff,
    const __hip_bfloat16* __restrict__ W1t, const float* __restrict__ b1,
    __hip_bfloat16* __restrict__ hq)
{
    __shared__ short Asl[2][128 * 32];
    __shared__ short Bsl[2][128 * 32];
    int tid = threadIdx.x;
    int wave = tid >> 6, lane = tid & 63;
    int m0 = blockIdx.y * 128, n0 = blockIdx.x * 128;

    int lrow = lane >> 2;
    int cg   = lane & 3;
    int ss   = (lane >> 3) & 3;
    int gq   = (cg - ss) & 3;

    // preload 10 row-offsets for this lane's two A rows
    unsigned o0[Kc], o1[Kc];
    {
        const unsigned* ap0 = aoff + (size_t)(m0 + wave * 32 + lrow) * 16;
        const unsigned* ap1 = ap0 + 16 * 16;
        #pragma unroll
        for (int j = 0; j < Kc; ++j) { o0[j] = ap0[j]; o1[j] = ap1[j]; }
    }
    const short* Eb = (const short*)encb;
    const short* Bb = (const short*)W1t;
    const short* gB0 = Bb + (size_t)(n0 + wave * 32 + lrow) * 1280 + gq * 8;
    const short* gB1 = gB0 + (size_t)16 * 1280;

    int wm = wave >> 1, wn = wave & 1;
    int rrow = lane & 15, quad = lane >> 4;
    int srd  = (rrow >> 1) & 3;

    f32x4 acc[4][4];
    #pragma unroll
    for (int i = 0; i < 4; ++i)
        #pragma unroll
        for (int j = 0; j < 4; ++j)
            acc[i][j] = (f32x4){0.f, 0.f, 0.f, 0.f};

    #pragma unroll
    for (int kt = 0; kt < 20; ++kt) {
        int k0 = kt * 64;
        int slot = kt >> 1;                 // compile-time per unrolled iter
        int dbase = (kt & 1) * 64 + gq * 8; // within-slot column offset
        __syncthreads();
        #pragma unroll
        for (int s = 0; s < 2; ++s) {
            GLOAD_LDS16(Eb + o0[slot] + dbase + s * 32, &Asl[s][(wave * 32) * 32]);
            GLOAD_LDS16(Eb + o1[slot] + dbase + s * 32, &Asl[s][(wave * 32 + 16) * 32]);
            GLOAD_LDS16(gB0 + k0 + s * 32, &Bsl[s][(wave * 32) * 32]);
            GLOAD_LDS16(gB1 + k0 + s * 32, &Bsl[s][(wave * 32 + 16) * 32]);
        }
        __syncthreads();
        #pragma unroll
        for (int s = 0; s < 2; ++s) {
            short8 afr[4], bfr[4];
            #pragma unroll
            for (int mt = 0; mt < 4; ++mt) {
                int rowa = wm * 64 + mt * 16 + rrow;
                afr[mt] = *(const short8*)&Asl[s][rowa * 32 + ((quad + srd) & 3) * 8];
                int rowb = wn * 64 + mt * 16 + rrow;
                bfr[mt] = *(const short8*)&Bsl[s][rowb * 32 + ((quad + srd) & 3) * 8];
            }
            #pragma unroll
            for (int mt = 0; mt < 4; ++mt)
                #pragma unroll
                for (int nt = 0; nt < 4; ++nt)
                    acc[mt][nt] = __builtin_amdgcn_mfma_f32_16x16x32_bf16(
                        afr[mt], bfr[nt], acc[mt][nt], 0, 0, 0);
        }
    }

    #pragma unroll
    for (int mt = 0; mt < 4; ++mt) {
        #pragma unroll
        for (int nt = 0; nt < 4; ++nt) {
            int n = wn * 64 + nt * 16 + rrow;
            float bv = b1[n0 + n];
            #pragma unroll
            for (int i = 0; i < 4; ++i) {
                int m = m0 + wm * 64 + mt * 16 + quad * 4 + i;
                float v = fmaxf(acc[mt][nt][i] + bv, 0.f);
                hq[(size_t)m * 768 + 128 + n0 + n] = __float2bfloat16(v);
            }
        }
    }
}

// ---------------------------------------------------------------------------
// Kernel 3: generic bf16 MFMA GEMM. C = (A @ Bt^T + bias). BK=64.
// ---------------------------------------------------------------------------
template<bool HASBIAS, bool OUTBF16>
__global__ __launch_bounds__(256) void mfma_gemm_kernel(
    const __hip_bfloat16* __restrict__ A, int lda,
    const __hip_bfloat16* __restrict__ Bt, int ldbt, int Kloop,
    const float* __restrict__ bias,
    void* __restrict__ Cout, int ldc, int coff)
{
    __shared__ short Asl[2][128 * 32];
    __shared__ short Bsl[2][128 * 32];
    int tid = threadIdx.x;
    int wave = tid >> 6, lane = tid & 63;
    int m0 = blockIdx.y * 128, n0 = blockIdx.x * 128;

    int lrow = lane >> 2;
    int cg   = lane & 3;
    int ss   = (lane >> 3) & 3;
    int gq   = (cg - ss) & 3;
    const short* Ab = (const short*)A;
    const short* Bb = (const short*)Bt;
    const short* gA0 = Ab + (size_t)(m0 + wave * 32 + lrow) * lda + gq * 8;
    const short* gA1 = gA0 + (size_t)16 * lda;
    const short* gB0 = Bb + (size_t)(n0 + wave * 32 + lrow) * ldbt + gq * 8;
    const short* gB1 = gB0 + (size_t)16 * ldbt;

    int wm = wave >> 1, wn = wave & 1;
    int rrow = lane & 15, quad = lane >> 4;
    int srd  = (rrow >> 1) & 3;

    f32x4 acc[4][4];
    #pragma unroll
    for (int i = 0; i < 4; ++i)
        #pragma unroll
        for (int j = 0; j < 4; ++j)
            acc[i][j] = (f32x4){0.f, 0.f, 0.f, 0.f};

    for (int k0 = 0; k0 < Kloop; k0 += 64) {
        __syncthreads();
        #pragma unroll
        for (int s = 0; s < 2; ++s) {
            GLOAD_LDS16(gA0 + k0 + s * 32, &Asl[s][(wave * 32) * 32]);
            GLOAD_LDS16(gA1 + k0 + s * 32, &Asl[s][(wave * 32 + 16) * 32]);
            GLOAD_LDS16(gB0 + k0 + s * 32, &Bsl[s][(wave * 32) * 32]);
            GLOAD_LDS16(gB1 + k0 + s * 32, &Bsl[s][(wave * 32 + 16) * 32]);
        }
        __syncthreads();
        #pragma unroll
        for (int s = 0; s < 2; ++s) {
            short8 afr[4], bfr[4];
            #pragma unroll
            for (int mt = 0; mt < 4; ++mt) {
                int rowa = wm * 64 + mt * 16 + rrow;
                afr[mt] = *(const short8*)&Asl[s][rowa * 32 + ((quad + srd) & 3) * 8];
                int rowb = wn * 64 + mt * 16 + rrow;
                bfr[mt] = *(const short8*)&Bsl[s][rowb * 32 + ((quad + srd) & 3) * 8];
            }
            #pragma unroll
            for (int mt = 0; mt < 4; ++mt)
                #pragma unroll
                for (int nt = 0; nt < 4; ++nt)
                    acc[mt][nt] = __builtin_amdgcn_mfma_f32_16x16x32_bf16(
                        afr[mt], bfr[nt], acc[mt][nt], 0, 0, 0);
        }
    }

    #pragma unroll
    for (int mt = 0; mt < 4; ++mt) {
        #pragma unroll
        for (int nt = 0; nt < 4; ++nt) {
            int n = wn * 64 + nt * 16 + rrow;
            float bv = HASBIAS ? bias[n0 + n] : 0.f;
            #pragma unroll
            for (int i = 0; i < 4; ++i) {
                int m = m0 + wm * 64 + mt * 16 + quad * 4 + i;
                float v = acc[mt][nt][i] + bv;
                size_t off = (size_t)m * ldc + coff + n0 + n;
                if (OUTBF16) ((__hip_bfloat16*)Cout)[off] = __float2bfloat16(v);
                else         ((float*)Cout)[off] = v;
            }
        }
    }
}

// ---------------------------------------------------------------------------
// Kernel 3b: q = bf16(qp0 + qp1)  (split-K reduce)
// ---------------------------------------------------------------------------
__global__ __launch_bounds__(256) void qreduce_kernel(
    const float* __restrict__ p0, const float* __restrict__ p1,
    __hip_bfloat16* __restrict__ q)
{
    int i = (blockIdx.x * 256 + threadIdx.x) * 4;
    float4 a = *(const float4*)(p0 + i);
    float4 b = *(const float4*)(p1 + i);
    q[i + 0] = __float2bfloat16(a.x + b.x);
    q[i + 1] = __float2bfloat16(a.y + b.y);
    q[i + 2] = __float2bfloat16(a.z + b.z);
    q[i + 3] = __float2bfloat16(a.w + b.w);
}

// ---------------------------------------------------------------------------
// Kernel 4: MFMA flash attention, one block per (b,h), 4 waves.
// ---------------------------------------------------------------------------
__global__ __launch_bounds__(256) void attn_mfma_kernel(
    const __hip_bfloat16* __restrict__ q, const __hip_bfloat16* __restrict__ kvf,
    const u64* __restrict__ maskbits, __hip_bfloat16* __restrict__ att)
{
    constexpr int RP = 208;
    constexpr int QS = 40;
    constexpr int VS = 232;
    __shared__ short Qs[RP * QS];
    __shared__ short Ks[RP * QS];
    __shared__ short Vt[16 * VS];
    __shared__ short Ps[4][16 * VS];
    __shared__ u64 smask[RP][4];

    int b = blockIdx.x >> 3, h = blockIdx.x & 7;
    int t = threadIdx.x;
    int wave = t >> 6, lane = t & 63;
    int rrow = lane & 15, quad = lane >> 4;

    const short8 z8 = {0, 0, 0, 0, 0, 0, 0, 0};
    for (int idx = t; idx < RP * 2; idx += 256) {
        int r = idx >> 1, g = idx & 1;
        short8 qa = z8, ka = z8;
        if (r < Rc) {
            qa = *(const short8*)((const short*)q + ((size_t)(b * Rc + r)) * 128 + h * 16 + g * 8);
            ka = *(const short8*)((const short*)kvf + ((size_t)(b * Nc + r)) * 256 + h * 16 + g * 8);
        }
        *(short8*)&Qs[r * QS + g * 8] = qa;
        *(short8*)&Ks[r * QS + g * 8] = ka;
        *(short8*)&Qs[r * QS + 16 + g * 8] = z8;
        *(short8*)&Ks[r * QS + 16 + g * 8] = z8;
    }
    if (t < Rc) {
        const short* vp = (const short*)kvf + ((size_t)(b * Nc + t)) * 256 + 128 + h * 16;
        short8 v0 = *(const short8*)vp;
        short8 v1 = *(const short8*)(vp + 8);
        #pragma unroll
        for (int d = 0; d < 8; ++d) Vt[d * VS + t] = v0[d];
        #pragma unroll
        for (int d = 0; d < 8; ++d) Vt[(d + 8) * VS + t] = v1[d];
    }
    for (int idx = t; idx < 16 * 32; idx += 256) {
        int d = idx >> 5, cN = 200 + (idx & 31);
        if (cN < VS) Vt[d * VS + cN] = 0;
    }
    for (int idx = lane; idx < 16 * 16; idx += 64) {
        int rr = idx >> 4, cc = 208 + (idx & 15);
        Ps[wave][rr * VS + cc] = 0;
    }
    for (int idx = t; idx < RP * 4; idx += 256) {
        int r = idx >> 2, w = idx & 3;
        smask[r][w] = (r < Rc) ? maskbits[((size_t)b * Rc + r) * 4 + w] : ~0ull;
    }
    __syncthreads();

    for (int rt = wave; rt < 13; rt += 4) {
        short8 qf = *(const short8*)&Qs[(rt * 16 + rrow) * QS + quad * 8];
        f32x4 sacc[13];
        #pragma unroll
        for (int nt = 0; nt < 13; ++nt) {
            short8 kf = *(const short8*)&Ks[(nt * 16 + rrow) * QS + quad * 8];
            sacc[nt] = __builtin_amdgcn_mfma_f32_16x16x32_bf16(
                qf, kf, (f32x4){0.f, 0.f, 0.f, 0.f}, 0, 0, 0);
        }
        float inv[4];
        #pragma unroll
        for (int i = 0; i < 4; ++i) {
            int r = rt * 16 + quad * 4 + i;
            u64 wv0 = smask[r][0], wv1 = smask[r][1], wv2 = smask[r][2], wv3 = smask[r][3];
            float mx = -INFINITY;
            #pragma unroll
            for (int nt = 0; nt < 13; ++nt) {
                u64 w = (nt < 4) ? wv0 : (nt < 8) ? wv1 : (nt < 12) ? wv2 : wv3;
                int sh = ((nt & 3) << 4) + rrow;
                float s = ((w >> sh) & 1ull) ? sacc[nt][i] : -INFINITY;
                sacc[nt][i] = s;
                mx = fmaxf(mx, s);
            }
            mx = fmaxf(mx, __shfl_xor(mx, 1));
            mx = fmaxf(mx, __shfl_xor(mx, 2));
            mx = fmaxf(mx, __shfl_xor(mx, 4));
            mx = fmaxf(mx, __shfl_xor(mx, 8));
            float l = 0.f;
            #pragma unroll
            for (int nt = 0; nt < 13; ++nt) {
                float p = __expf(sacc[nt][i] - mx);
                sacc[nt][i] = p;
                l += p;
            }
            l += __shfl_xor(l, 1);
            l += __shfl_xor(l, 2);
            l += __shfl_xor(l, 4);
            l += __shfl_xor(l, 8);
            inv[i] = (l > 0.f) ? 1.f / l : 0.f;
        }
        #pragma unroll
        for (int nt = 0; nt < 13; ++nt)
            #pragma unroll
            for (int i = 0; i < 4; ++i)
                *(__hip_bfloat16*)&Ps[wave][(quad * 4 + i) * VS + nt * 16 + rrow] =
                    __float2bfloat16(sacc[nt][i]);
        f32x4 oacc = (f32x4){0.f, 0.f, 0.f, 0.f};
        #pragma unroll
        for (int kt = 0; kt < 7; ++kt) {
            short8 pf = *(const short8*)&Ps[wave][rrow * VS + kt * 32 + quad * 8];
            short8 vf = *(const short8*)&Vt[rrow * VS + kt * 32 + quad * 8];
            oacc = __builtin_amdgcn_mfma_f32_16x16x32_bf16(pf, vf, oacc, 0, 0, 0);
        }
        #pragma unroll
        for (int i = 0; i < 4; ++i) {
            int r = rt * 16 + quad * 4 + i;
            if (r < Rc)
                att[((size_t)(b * Rc + r)) * 128 + h * 16 + rrow] =
                    __float2bfloat16(oacc[i] * inv[i]);
        }
    }
}

// ---------------------------------------------------------------------------
// Kernel 5: logits = 10*tanh((mh @ enc^T)/sqrt(128)) masked via maskbits.
// ---------------------------------------------------------------------------
__global__ __launch_bounds__(256) void logits_mfma_kernel(
    const __hip_bfloat16* __restrict__ mh, const __hip_bfloat16* __restrict__ encb,
    const u64* __restrict__ maskbits, float* __restrict__ out)
{
    __shared__ short Asl[128 * 32];
    __shared__ short Bsl[128 * 32];
    __shared__ u64 sm[128][4];
    int b = blockIdx.x;
    int m0 = blockIdx.y * 128;
    int n0 = blockIdx.z * 128;
    int tid = threadIdx.x;
    int wave = tid >> 6, lane = tid & 63;

    for (int idx = tid; idx < 512; idx += 256) {
        int r = idx >> 2, w = idx & 3;
        int gr = m0 + r;
        sm[r][w] = (gr < Rc) ? maskbits[((size_t)b * Rc + gr) * 4 + w] : 0ull;
    }

    int lrow = lane >> 2;
    int cg   = lane & 3;
    int ss   = (lane >> 3) & 3;
    int gq   = (cg - ss) & 3;
    const short* Ab = (const short*)(mh + (size_t)b * Rc * 128);
    const short* Bb = (const short*)(encb + (size_t)b * Nc * 128);
    const short* gA0 = Ab + (size_t)(m0 + wave * 32 + lrow) * 128 + gq * 8;
    const short* gA1 = gA0 + (size_t)16 * 128;
    const short* gB0 = Bb + (size_t)(n0 + wave * 32 + lrow) * 128 + gq * 8;
    const short* gB1 = gB0 + (size_t)16 * 128;
    short* lA0 = &Asl[(wave * 32) * 32];
    short* lA1 = &Asl[(wave * 32 + 16) * 32];
    short* lB0 = &Bsl[(wave * 32) * 32];
    short* lB1 = &Bsl[(wave * 32 + 16) * 32];

    int wm = wave >> 1, wn = wave & 1;
    int rrow = lane & 15, quad = lane >> 4;
    int srd  = (rrow >> 1) & 3;

    f32x4 acc[4][4];
    #pragma unroll
    for (int i = 0; i < 4; ++i)
        #pragma unroll
        for (int j = 0; j < 4; ++j)
            acc[i][j] = (f32x4){0.f, 0.f, 0.f, 0.f};

    for (int k0 = 0; k0 < 128; k0 += 32) {
        __syncthreads();
        GLOAD_LDS16(gA0 + k0, lA0);
        GLOAD_LDS16(gA1 + k0, lA1);
        GLOAD_LDS16(gB0 + k0, lB0);
        GLOAD_LDS16(gB1 + k0, lB1);
        __syncthreads();
        short8 afr[4], bfr[4];
        #pragma unroll
        for (int mt = 0; mt < 4; ++mt) {
            int rowa = wm * 64 + mt * 16 + rrow;
            afr[mt] = *(const short8*)&Asl[rowa * 32 + ((quad + srd) & 3) * 8];
            int rowb = wn * 64 + mt * 16 + rrow;
            bfr[mt] = *(const short8*)&Bsl[rowb * 32 + ((quad + srd) & 3) * 8];
        }
        #pragma unroll
        for (int mt = 0; mt < 4; ++mt)
            #pragma unroll
            for (int nt = 0; nt < 4; ++nt)
                acc[mt][nt] = __builtin_amdgcn_mfma_f32_16x16x32_bf16(
                    afr[mt], bfr[nt], acc[mt][nt], 0, 0, 0);
    }

    const float scale = 0.08838834764831843f;
    #pragma unroll
    for (int mt = 0; mt < 4; ++mt) {
        #pragma unroll
        for (int nt = 0; nt < 4; ++nt) {
            int n = n0 + wn * 64 + nt * 16 + rrow;
            #pragma unroll
            for (int i = 0; i < 4; ++i) {
                int r = m0 + wm * 64 + mt * 16 + quad * 4 + i;
                if (r < Rc && n < Nc) {
                    u64 w = sm[r - m0][n >> 6];
                    float lg = ((w >> (n & 63)) & 1ull)
                             ? 10.f * tanhf(acc[mt][nt][i] * scale) : -INFINITY;
                    out[((size_t)b * Rc + r) * Nc + n] = lg;
                }
            }
        }
    }
}

// ---------------------------------------------------------------------------
// Kernel 6: row softmax over N=200, in place.
// ---------------------------------------------------------------------------
__global__ __launch_bounds__(64) void softmax_kernel(float* __restrict__ out)
{
    int br = blockIdx.x;
    float* row = out + (size_t)br * Nc;
    int t = threadIdx.x;
    float v[4]; float m = -INFINITY;
    #pragma unroll
    for (int j = 0; j < 4; ++j) {
        int n = t + 64 * j;
        v[j] = (n < Nc) ? row[n] : -INFINITY;
        m = fmaxf(m, v[j]);
    }
    #pragma unroll
    for (int off = 32; off > 0; off >>= 1) m = fmaxf(m, __shfl_xor(m, off));
    float e[4]; float s = 0.f;
    #pragma unroll
    for (int j = 0; j < 4; ++j) {
        e[j] = (v[j] == -INFINITY) ? 0.f : expf(v[j] - m);
        s += e[j];
    }
    #pragma unroll
    for (int off = 32; off > 0; off >>= 1) s += __shfl_xor(s, off);
    float inv = 1.f / s;
    #pragma unroll
    for (int j = 0; j < 4; ++j) {
        int n = t + 64 * j;
        if (n < Nc) row[n] = e[j] * inv;
    }
}

// ---------------------------------------------------------------------------
extern "C" void kernel_launch(void* const* d_in, const int* in_sizes, int n_in,
                              void* d_out, int out_size, void* d_ws, size_t ws_size,
                              hipStream_t stream)
{
    const float* enc  = (const float*)d_in[0];
    const float* dist = (const float*)d_in[1];
    const float* mask = (const float*)d_in[2];
    const int*   cur  = (const int*)d_in[3];
    const float* Wq   = (const float*)d_in[4];
    const float* Wk   = (const float*)d_in[5];
    const float* Wv   = (const float*)d_in[6];
    const float* Wmhc = (const float*)d_in[7];
    const float* bmhc = (const float*)d_in[8];
    const float* W1   = (const float*)d_in[9];
    const float* b1   = (const float*)d_in[10];
    const float* W2   = (const float*)d_in[11];
    const float* b2   = (const float*)d_in[12];
    float* out = (float*)d_out;

    char* ws = (char*)d_ws;
    size_t off = 0;
    auto alloc = [&](size_t bytes) { char* p = ws + off; off += (bytes + 255) & ~(size_t)255; return p; };
    __hip_bfloat16* W1t  = (__hip_bfloat16*)alloc((size_t)640 * 1280 * 2);
    __hip_bfloat16* Wkvt = (__hip_bfloat16*)alloc((size_t)256 * 128 * 2);
    __hip_bfloat16* Wmt  = (__hip_bfloat16*)alloc((size_t)128 * 128 * 2);
    __hip_bfloat16* Wcat = (__hip_bfloat16*)alloc((size_t)128 * 768 * 2);
    float* bq = (float*)alloc((size_t)128 * 4);
    // encb: rows [0, Bc*Nc) = enc bf16; rows [Bc*Nc, Bc*Nc+BRc) = mean rows
    __hip_bfloat16* encb = (__hip_bfloat16*)alloc((size_t)(Bc * Nc + BRc + 64) * Dc * 2);
    unsigned* aoff = (unsigned*)alloc((size_t)BRc * 16 * 4);
    __hip_bfloat16* hq   = (__hip_bfloat16*)alloc((size_t)BRc * 768 * 2);
    float* qp0 = (float*)alloc((size_t)BRc * 128 * 4);
    float* qp1 = (float*)alloc((size_t)BRc * 128 * 4);
    __hip_bfloat16* q    = (__hip_bfloat16*)alloc((size_t)BRc * 128 * 2);
    __hip_bfloat16* kvf  = (__hip_bfloat16*)alloc((size_t)Bc * Nc * 256 * 2);
    __hip_bfloat16* att  = (__hip_bfloat16*)alloc((size_t)BRc * 128 * 2);
    __hip_bfloat16* mh   = (__hip_bfloat16*)alloc((size_t)(BRc + 64) * 128 * 2);
    u64* maskbits = (u64*)alloc((size_t)BRc * 4 * 8);

    // 1) weight preprocessing
    prep_kernel<<<930, 256, 0, stream>>>(W1, W2, Wq, Wmhc, Wk, Wv, b2, enc,
                                         W1t, Wkvt, Wmt, Wcat, bq, encb);
    // 2) kNN select + offset table + mean rows + bitmask
    knn_gather_kernel<<<BRc, 128, 0, stream>>>(enc, dist, mask, cur,
                                               encb, aoff, hq, maskbits);
    // 3) kvf = enc @ [Wk|Wv]
    mfma_gemm_kernel<false, true><<<dim3(2, (Bc * Nc) / 128), 256, 0, stream>>>(
        encb, 128, Wkvt, 128, 128, nullptr, kvf, 256, 0);
    // 4) hq[:,128:768] = relu(gather(encb) @ W1t^T + b1)
    gemm1_kernel<<<dim3(5, BRc / 128), 256, 0, stream>>>(encb, aoff, W1t, b1, hq);
    // 5) q = hq @ Wcat^T + bq, split-K=2 (fp32 partials), then reduce->bf16
    mfma_gemm_kernel<true, false><<<dim3(1, BRc / 128), 256, 0, stream>>>(
        hq, 768, Wcat, 768, 384, bq, qp0, 128, 0);
    mfma_gemm_kernel<false, false><<<dim3(1, BRc / 128), 256, 0, stream>>>(
        hq + 384, 768, Wcat + 384, 768, 384, nullptr, qp1, 128, 0);
    qreduce_kernel<<<(BRc * 128) / 1024, 256, 0, stream>>>(qp0, qp1, q);
    // 6) MFMA flash attention
    attn_mfma_kernel<<<Bc * Hc, 256, 0, stream>>>(q, kvf, maskbits, att);
    // 7) mh = att @ Wmhc + b_mhc (bf16 out)
    mfma_gemm_kernel<true, true><<<dim3(1, BRc / 128), 256, 0, stream>>>(
        att, 128, Wmt, 128, 128, bmhc, mh, 128, 0);
    // 8) logits (MFMA) + tanh + maskbits
    logits_mfma_kernel<<<dim3(Bc, 2, 2), 256, 0, stream>>>(mh, encb, maskbits, out);
    // 9) softmax
    softmax_kernel<<<BRc, 64, 0, stream>>>(out);
}